// Round 5
// baseline (84.888 us; speedup 1.0000x reference)
//
#include <hip/hip_runtime.h>

// ABELSpline: B=1024, D=128, DENSITY=259, ODIM=64, IDIM=512
// out[b,o] = direct[b,o] + sum_n c_n*(exp(z[b,8o+n]) - exp(z[b,8o+4+n])), c_n=(n+1)^-2
// direct[b,o] = sum_{d,k} w[b,d,k] * dtab[d*259 + p[b,d] + k, o]
// z[b,j]      = sum_{d,k} w[b,d,k] * itab[d*259 + p[b,d] + k, j]
// p = floor(256*x); p+3 <= 258 so the reference's mod never wraps.
//
// Round 4: column-sliced across XCDs (round 3, FETCH 473->52MB) + occupancy fix:
// 512 threads = 8 waves, one batch row per wave -> 1024 blocks x 8 waves =
// 32 waves/CU (was grid-capped at 16). Direct phase re-laid so d (not r) varies
// across lanes -> LDS stride 16B hits all 32 banks (was 8-way conflict).

constexpr int BATCH = 1024;
constexpr int DIN = 128;
constexpr int DENSITY = 259;
constexpr int ODIM = 64;
constexpr int IDIM = 512;
constexpr int SLICES = 8;           // = #XCDs; 8 outputs / 64 indirect cols each
constexpr int RPB = 8;              // batch rows per block (= waves per block)
constexpr int TPB = 512;

__device__ __forceinline__ void fma4(float4& a, float s, const float4 v) {
    a.x = fmaf(s, v.x, a.x);
    a.y = fmaf(s, v.y, a.y);
    a.z = fmaf(s, v.z, a.z);
    a.w = fmaf(s, v.w, a.w);
}

__device__ __forceinline__ void add4(float4& a, const float4 t) {
    a.x += t.x; a.y += t.y; a.z += t.z; a.w += t.w;
}

__device__ __forceinline__ float4 shfl_xor4(float4 v, int m) {
    return make_float4(__shfl_xor(v.x, m), __shfl_xor(v.y, m),
                       __shfl_xor(v.z, m), __shfl_xor(v.w, m));
}

__global__ __launch_bounds__(TPB, 8) void abel_spline_kernel(
    const float* __restrict__ x,
    const float* __restrict__ dtab,
    const float* __restrict__ itab,
    float* __restrict__ out)
{
    __shared__ float4 s_w[RPB][DIN];     // spline weights per (row, dim)
    __shared__ int    s_base[RPB][DIN];  // d*259 + floor(256*x)
    __shared__ float  s_z[RPB][64];      // z for this slice's 64 indirect cols
    __shared__ float4 s_dir4[RPB][2];    // direct sums (8 cols = 2 float4) per row

    const int bid   = blockIdx.x;
    const int slice = bid & (SLICES - 1);   // round-robin -> XCD-pinned stripe
    const int chunk = bid >> 3;             // 0..127
    const int tid   = threadIdx.x;
    const int wv    = tid >> 6;             // 0..7 == batch row within chunk
    const int lane  = tid & 63;
    const int rowbase = chunk * RPB;

    // ---- phase 1: weights + base row index for all (r,d) pairs
    for (int i = tid; i < RPB * DIN; i += TPB) {
        const int r = i >> 7;
        const int d = i & 127;
        float xv = x[(rowbase + r) * DIN + d];
        float t  = xv * 256.0f;     // scale = DENSITY-3 = 256
        float fl = floorf(t);
        float f  = t - fl;
        float f2 = f * f;
        float f3 = f2 * f;
        float om = 1.0f - f;
        float w0 = om * om * om * (1.0f / 6.0f);
        float w1 = (3.0f * f3 - 6.0f * f2 + 4.0f) * (1.0f / 6.0f);
        float w2 = (-3.0f * f3 + 3.0f * f2 + 3.0f * f + 1.0f) * (1.0f / 6.0f);
        float w3 = f3 * (1.0f / 6.0f);
        s_w[r][d]    = make_float4(w0, w1, w2, w3);
        s_base[r][d] = d * DENSITY + (int)fl;
    }
    __syncthreads();

    // ---- phase 2a: indirect stripe, one row per wave.
    // lane = knot q (lane>>4) x col-quad c4 (lane&15); wave-load = 4 knots x 64 floats.
    const int q  = lane >> 4;
    const int c4 = lane & 15;
    const float* __restrict__ itL = itab + (size_t)q * IDIM + slice * 64 + c4 * 4;

    float4 aI = make_float4(0.f, 0.f, 0.f, 0.f);
    #pragma unroll 4
    for (int d = 0; d < DIN; ++d) {
        const int   bI = s_base[wv][d];                      // wave-uniform (broadcast)
        const float wI = ((const float*)&s_w[wv][d])[q];     // 4 addrs, 4 banks
        float4 v = *(const float4*)(itL + (size_t)bI * IDIM);
        fma4(aI, wI, v);
    }
    // reduce over knot q (lane bits 4-5)
    add4(aI, shfl_xor4(aI, 16));
    add4(aI, shfl_xor4(aI, 32));
    if (q == 0) reinterpret_cast<float4*>(s_z[wv])[c4] = aI;

    // ---- phase 2b: direct stripe (8 cols), one row per wave.
    // lane = dd(3b, bits 3-5) | qD(2b, bits 1-2) | jD(1b, bit 0); 8 dims at once.
    const int dd = lane >> 3;
    const int qD = (lane >> 1) & 3;
    const int jD = lane & 1;
    const float* __restrict__ dtL = dtab + (size_t)qD * ODIM + slice * 8 + jD * 4;

    float4 aD = make_float4(0.f, 0.f, 0.f, 0.f);
    #pragma unroll 2
    for (int d0 = 0; d0 < DIN; d0 += 8) {
        const int   d  = d0 + dd;
        const int   bD = s_base[wv][d];                      // 8 addrs, 8 banks
        const float wD = ((const float*)&s_w[wv][d])[qD];    // stride 16B -> 32 banks
        float4 u = *(const float4*)(dtL + (size_t)bD * ODIM);
        fma4(aD, wD, u);
    }
    // reduce over qD (bits 1-2) and dd (bits 3-5)
    add4(aD, shfl_xor4(aD, 2));
    add4(aD, shfl_xor4(aD, 4));
    add4(aD, shfl_xor4(aD, 8));
    add4(aD, shfl_xor4(aD, 16));
    add4(aD, shfl_xor4(aD, 32));
    if (lane < 2) s_dir4[wv][lane] = aD;     // lane==jD holds cols jD*4..jD*4+3
    __syncthreads();

    // ---- phase 3: epilogue, 64 threads = 8 rows x 8 outputs of this slice
    if (tid < RPB * 8) {
        const int r  = tid >> 3;
        const int oo = tid & 7;
        float dir = ((const float*)&s_dir4[r][oo >> 2])[oo & 3];
        const float* zp = s_z[r] + oo * 8;
        float pos = __expf(zp[0]) + 0.25f * __expf(zp[1])
                  + (1.0f / 9.0f) * __expf(zp[2]) + 0.0625f * __expf(zp[3]);
        float neg = __expf(zp[4]) + 0.25f * __expf(zp[5])
                  + (1.0f / 9.0f) * __expf(zp[6]) + 0.0625f * __expf(zp[7]);
        out[(rowbase + r) * ODIM + slice * 8 + oo] = dir + pos - neg;
    }
}

extern "C" void kernel_launch(void* const* d_in, const int* in_sizes, int n_in,
                              void* d_out, int out_size, void* d_ws, size_t ws_size,
                              hipStream_t stream) {
    const float* x    = (const float*)d_in[0];
    const float* dtab = (const float*)d_in[1];
    const float* itab = (const float*)d_in[2];
    float* out = (float*)d_out;
    hipLaunchKernelGGL(abel_spline_kernel, dim3(BATCH / RPB * SLICES), dim3(TPB), 0, stream,
                       x, dtab, itab, out);
}

// Round 6
// 75.466 us; speedup vs baseline: 1.1248x; 1.1248x over previous
//
#include <hip/hip_runtime.h>

// ABELSpline: B=1024, D=128, DENSITY=259, ODIM=64, IDIM=512
// out[b,o] = direct[b,o] + sum_n c_n*(exp(z[b,8o+n]) - exp(z[b,8o+4+n])), c_n=(n+1)^-2
// direct[b,o] = sum_{d,k} w[b,d,k] * dtab[d*259 + p[b,d] + k, o]
// z[b,j]      = sum_{d,k} w[b,d,k] * itab[d*259 + p[b,d] + k, j]
// p = floor(256*x); p+3 <= 258 so the reference's mod never wraps.
//
// Round 5: round-3 structure (column-sliced across XCDs, FETCH 52MB, 62.8us)
// with its two measured defects fixed:
//  - grid-capped occupancy: RPB 8->4, grid 2048 blocks x 4 waves = 32 waves/CU cap
//    (round 3 was 16). One row per wave, manual 2-dim body + unroll 2 keeps
//    2-4 gathers in flight (round 4's launch_bounds clamp killed MLP: VGPR=20).
//  - direct-phase 8-way LDS bank conflict (1.58M): d now varies across lanes
//    (16B stride -> all banks), r is wave-uniform. Measured clean in round 4.

constexpr int BATCH = 1024;
constexpr int DIN = 128;
constexpr int DENSITY = 259;
constexpr int ODIM = 64;
constexpr int IDIM = 512;
constexpr int SLICES = 8;           // = #XCDs; 8 outputs / 64 indirect cols each
constexpr int RPB = 4;              // batch rows per block (= waves per block)
constexpr int TPB = 256;

__device__ __forceinline__ void fma4(float4& a, float s, const float4 v) {
    a.x = fmaf(s, v.x, a.x);
    a.y = fmaf(s, v.y, a.y);
    a.z = fmaf(s, v.z, a.z);
    a.w = fmaf(s, v.w, a.w);
}

__device__ __forceinline__ void add4(float4& a, const float4 t) {
    a.x += t.x; a.y += t.y; a.z += t.z; a.w += t.w;
}

__device__ __forceinline__ float4 shfl_xor4(float4 v, int m) {
    return make_float4(__shfl_xor(v.x, m), __shfl_xor(v.y, m),
                       __shfl_xor(v.z, m), __shfl_xor(v.w, m));
}

__global__ __launch_bounds__(TPB) void abel_spline_kernel(
    const float* __restrict__ x,
    const float* __restrict__ dtab,
    const float* __restrict__ itab,
    float* __restrict__ out)
{
    __shared__ float4 s_w[RPB][DIN];     // spline weights per (row, dim)
    __shared__ int    s_base[RPB][DIN];  // d*259 + floor(256*x)
    __shared__ float  s_z[RPB][64];      // z for this slice's 64 indirect cols
    __shared__ float4 s_dir4[RPB][2];    // direct sums (8 cols = 2 float4) per row

    const int bid   = blockIdx.x;
    const int slice = bid & (SLICES - 1);   // round-robin -> XCD-pinned stripe
    const int chunk = bid >> 3;             // 0..255
    const int tid   = threadIdx.x;
    const int wv    = tid >> 6;             // 0..3 == batch row within chunk
    const int lane  = tid & 63;
    const int rowbase = chunk * RPB;

    // ---- phase 1: weights + base row index for all (r,d) pairs (2 iters)
    for (int i = tid; i < RPB * DIN; i += TPB) {
        const int r = i >> 7;
        const int d = i & 127;
        float xv = x[(rowbase + r) * DIN + d];
        float t  = xv * 256.0f;     // scale = DENSITY-3 = 256
        float fl = floorf(t);
        float f  = t - fl;
        float f2 = f * f;
        float f3 = f2 * f;
        float om = 1.0f - f;
        float w0 = om * om * om * (1.0f / 6.0f);
        float w1 = (3.0f * f3 - 6.0f * f2 + 4.0f) * (1.0f / 6.0f);
        float w2 = (-3.0f * f3 + 3.0f * f2 + 3.0f * f + 1.0f) * (1.0f / 6.0f);
        float w3 = f3 * (1.0f / 6.0f);
        s_w[r][d]    = make_float4(w0, w1, w2, w3);
        s_base[r][d] = d * DENSITY + (int)fl;
    }
    __syncthreads();

    // ---- phase 2a: indirect stripe, one row per wave.
    // lane = knot q (lane>>4) x col-quad c4 (lane&15); wave-load covers a full
    // (row,dim) window: 4 knots x 16 float4 = 1KB. 2 dims per body, unroll 2.
    const int q  = lane >> 4;
    const int c4 = lane & 15;
    const float* __restrict__ itL = itab + (size_t)q * IDIM + slice * 64 + c4 * 4;

    float4 aI = make_float4(0.f, 0.f, 0.f, 0.f);
    #pragma unroll 2
    for (int d = 0; d < DIN; d += 2) {
        const int   b0 = s_base[wv][d];
        const int   b1 = s_base[wv][d + 1];
        const float w0 = ((const float*)&s_w[wv][d])[q];
        const float w1 = ((const float*)&s_w[wv][d + 1])[q];
        float4 v0 = *(const float4*)(itL + (size_t)b0 * IDIM);
        float4 v1 = *(const float4*)(itL + (size_t)b1 * IDIM);
        fma4(aI, w0, v0);
        fma4(aI, w1, v1);
    }
    // reduce over knot q (lane bits 4-5)
    add4(aI, shfl_xor4(aI, 16));
    add4(aI, shfl_xor4(aI, 32));
    if (q == 0) reinterpret_cast<float4*>(s_z[wv])[c4] = aI;

    // ---- phase 2b: direct stripe (8 cols), one row per wave.
    // lane = dd(3b, bits 3-5) | qD(2b, bits 1-2) | jD(1b, bit 0); 8 dims/load.
    // LDS addrs: s_w[wv][d0+dd] component qD -> stride 16B, 32 distinct banks.
    const int dd = lane >> 3;
    const int qD = (lane >> 1) & 3;
    const int jD = lane & 1;
    const float* __restrict__ dtL = dtab + (size_t)qD * ODIM + slice * 8 + jD * 4;

    float4 aD = make_float4(0.f, 0.f, 0.f, 0.f);
    #pragma unroll 2
    for (int d0 = 0; d0 < DIN; d0 += 8) {
        const int   d  = d0 + dd;
        const int   bD = s_base[wv][d];
        const float wD = ((const float*)&s_w[wv][d])[qD];
        float4 u = *(const float4*)(dtL + (size_t)bD * ODIM);
        fma4(aD, wD, u);
    }
    // reduce over qD (bits 1-2) and dd (bits 3-5)
    add4(aD, shfl_xor4(aD, 2));
    add4(aD, shfl_xor4(aD, 4));
    add4(aD, shfl_xor4(aD, 8));
    add4(aD, shfl_xor4(aD, 16));
    add4(aD, shfl_xor4(aD, 32));
    if (lane < 2) s_dir4[wv][lane] = aD;     // lane==jD holds cols jD*4..jD*4+3
    __syncthreads();

    // ---- phase 3: epilogue, 32 threads = 4 rows x 8 outputs of this slice
    if (tid < RPB * 8) {
        const int r  = tid >> 3;
        const int oo = tid & 7;
        float dir = ((const float*)&s_dir4[r][oo >> 2])[oo & 3];
        const float* zp = s_z[r] + oo * 8;
        float pos = __expf(zp[0]) + 0.25f * __expf(zp[1])
                  + (1.0f / 9.0f) * __expf(zp[2]) + 0.0625f * __expf(zp[3]);
        float neg = __expf(zp[4]) + 0.25f * __expf(zp[5])
                  + (1.0f / 9.0f) * __expf(zp[6]) + 0.0625f * __expf(zp[7]);
        out[(rowbase + r) * ODIM + slice * 8 + oo] = dir + pos - neg;
    }
}

extern "C" void kernel_launch(void* const* d_in, const int* in_sizes, int n_in,
                              void* d_out, int out_size, void* d_ws, size_t ws_size,
                              hipStream_t stream) {
    const float* x    = (const float*)d_in[0];
    const float* dtab = (const float*)d_in[1];
    const float* itab = (const float*)d_in[2];
    float* out = (float*)d_out;
    hipLaunchKernelGGL(abel_spline_kernel, dim3(BATCH / RPB * SLICES), dim3(TPB), 0, stream,
                       x, dtab, itab, out);
}

// Round 7
// 71.496 us; speedup vs baseline: 1.1873x; 1.0555x over previous
//
#include <hip/hip_runtime.h>

// ABELSpline: B=1024, D=128, DENSITY=259, ODIM=64, IDIM=512
// out[b,o] = direct[b,o] + sum_n c_n*(exp(z[b,8o+n]) - exp(z[b,8o+4+n])), c_n=(n+1)^-2
// direct[b,o] = sum_{d,k} w[b,d,k] * dtab[d*259 + p[b,d] + k, o]
// z[b,j]      = sum_{d,k} w[b,d,k] * itab[d*259 + p[b,d] + k, j]
// p = floor(256*x); p+3 <= 258 so the reference's mod never wraps.
//
// Round 6: round-3 structure restored (RPB=8, TPB=256, 2 rows/wave -> FETCH 52MB,
// VGPR 40, 62.8us) with its one measured defect fixed and MLP doubled:
//  - LDS transposed+padded: s_w[DIN][9](float4), s_base[DIN][9]. Direct-phase
//    lane-varying index (rD,qD) now strides 16B/4B -> 32 banks / 8 broadcast
//    addrs, killing the 8-way conflict (was 1.58M cycles).
//  - indirect body: 2 rows x 2 dims = 4 independent gathers in flight.
// Round 4/5 lesson: RPB<8 blows up L2-miss traffic (52->150MB); 1-row-per-wave
// lets the compiler serialize gathers (VGPR=20). Both avoided here.

constexpr int BATCH = 1024;
constexpr int DIN = 128;
constexpr int DENSITY = 259;
constexpr int ODIM = 64;
constexpr int IDIM = 512;
constexpr int SLICES = 8;           // = #XCDs; 8 outputs / 64 indirect cols each
constexpr int RPB = 8;              // batch rows per block
constexpr int TPB = 256;            // 4 waves; wave wv owns rows 2wv, 2wv+1 (indirect)
constexpr int PAD = 9;              // padded row stride for transposed LDS

__device__ __forceinline__ void fma4(float4& a, float s, const float4 v) {
    a.x = fmaf(s, v.x, a.x);
    a.y = fmaf(s, v.y, a.y);
    a.z = fmaf(s, v.z, a.z);
    a.w = fmaf(s, v.w, a.w);
}

__device__ __forceinline__ void add4(float4& a, const float4 t) {
    a.x += t.x; a.y += t.y; a.z += t.z; a.w += t.w;
}

__device__ __forceinline__ float4 shfl_xor4(float4 v, int m) {
    return make_float4(__shfl_xor(v.x, m), __shfl_xor(v.y, m),
                       __shfl_xor(v.z, m), __shfl_xor(v.w, m));
}

__global__ __launch_bounds__(TPB) void abel_spline_kernel(
    const float* __restrict__ x,
    const float* __restrict__ dtab,
    const float* __restrict__ itab,
    float* __restrict__ out)
{
    __shared__ float4 s_w[DIN][PAD];     // [d][r] spline weights (transposed, padded)
    __shared__ int    s_base[DIN][PAD];  // [d][r] d*259 + floor(256*x)
    __shared__ float  s_z[RPB][64];      // z for this slice's 64 indirect cols
    __shared__ float4 s_dirp[4][16];     // per-wave direct partials: [wave][rD*2+jD]

    const int bid   = blockIdx.x;
    const int slice = bid & (SLICES - 1);   // round-robin -> XCD-pinned stripe
    const int chunk = bid >> 3;             // 0..127
    const int tid   = threadIdx.x;
    const int wv    = tid >> 6;             // 0..3
    const int lane  = tid & 63;
    const int rowbase = chunk * RPB;

    // ---- phase 1: weights + base index; r wave-uniform, d lane-consecutive
    for (int i = tid; i < RPB * DIN; i += TPB) {
        const int r = i >> 7;       // 0..7
        const int d = i & 127;
        float xv = x[(rowbase + r) * DIN + d];   // coalesced
        float t  = xv * 256.0f;     // scale = DENSITY-3 = 256
        float fl = floorf(t);
        float f  = t - fl;
        float f2 = f * f;
        float f3 = f2 * f;
        float om = 1.0f - f;
        float w0 = om * om * om * (1.0f / 6.0f);
        float w1 = (3.0f * f3 - 6.0f * f2 + 4.0f) * (1.0f / 6.0f);
        float w2 = (-3.0f * f3 + 3.0f * f2 + 3.0f * f + 1.0f) * (1.0f / 6.0f);
        float w3 = f3 * (1.0f / 6.0f);
        s_w[d][r]    = make_float4(w0, w1, w2, w3);
        s_base[d][r] = d * DENSITY + (int)fl;
    }
    __syncthreads();

    // ---- phase 2a: indirect stripe, 2 rows per wave, 2 dims per body (MLP=4).
    // lane = knot q (lane>>4) x col-quad c4 (lane&15).
    const int q  = lane >> 4;
    const int c4 = lane & 15;
    const float* __restrict__ itL = itab + (size_t)q * IDIM + slice * 64 + c4 * 4;
    const int r0 = 2 * wv, r1 = 2 * wv + 1;

    float4 aI0 = make_float4(0.f, 0.f, 0.f, 0.f);
    float4 aI1 = make_float4(0.f, 0.f, 0.f, 0.f);
    #pragma unroll 2
    for (int d = 0; d < DIN; d += 2) {
        const int   b00 = s_base[d][r0];
        const int   b10 = s_base[d][r1];
        const int   b01 = s_base[d + 1][r0];
        const int   b11 = s_base[d + 1][r1];
        const float w00 = ((const float*)&s_w[d][r0])[q];
        const float w10 = ((const float*)&s_w[d][r1])[q];
        const float w01 = ((const float*)&s_w[d + 1][r0])[q];
        const float w11 = ((const float*)&s_w[d + 1][r1])[q];
        float4 v00 = *(const float4*)(itL + (size_t)b00 * IDIM);
        float4 v10 = *(const float4*)(itL + (size_t)b10 * IDIM);
        float4 v01 = *(const float4*)(itL + (size_t)b01 * IDIM);
        float4 v11 = *(const float4*)(itL + (size_t)b11 * IDIM);
        fma4(aI0, w00, v00);
        fma4(aI1, w10, v10);
        fma4(aI0, w01, v01);
        fma4(aI1, w11, v11);
    }
    // reduce over knot q (lane bits 4-5)
    add4(aI0, shfl_xor4(aI0, 16));
    add4(aI0, shfl_xor4(aI0, 32));
    add4(aI1, shfl_xor4(aI1, 16));
    add4(aI1, shfl_xor4(aI1, 32));
    if (q == 0) {
        reinterpret_cast<float4*>(s_z[r0])[c4] = aI0;
        reinterpret_cast<float4*>(s_z[r1])[c4] = aI1;
    }

    // ---- phase 2b: direct stripe (8 cols); wave wv covers dims d ≡ wv (mod 4),
    // lanes cover rD(3b)|qD(2b)|jD(1b). LDS reads now conflict-free:
    //   s_base[d][rD]: 8 distinct addrs (stride 4B) -> 8 banks, 8-way broadcast
    //   s_w[d][rD][qD]: 4*rD+qD -> 32 distinct banks
    const int rD = lane >> 3;
    const int qD = (lane >> 1) & 3;
    const int jD = lane & 1;
    const float* __restrict__ dtL = dtab + (size_t)qD * ODIM + slice * 8 + jD * 4;

    float4 aD = make_float4(0.f, 0.f, 0.f, 0.f);
    #pragma unroll 2
    for (int d = wv; d < DIN; d += 4) {
        const int   bD = s_base[d][rD];
        const float wD = ((const float*)&s_w[d][rD])[qD];
        float4 u = *(const float4*)(dtL + (size_t)bD * ODIM);
        fma4(aD, wD, u);
    }
    // reduce over knot qD (lane bits 1-2)
    add4(aD, shfl_xor4(aD, 2));
    add4(aD, shfl_xor4(aD, 4));
    if (qD == 0) s_dirp[wv][rD * 2 + jD] = aD;
    __syncthreads();

    // ---- phase 3: epilogue, 64 threads = 8 rows x 8 outputs of this slice
    if (tid < RPB * 8) {
        const int r  = tid >> 3;
        const int oo = tid & 7;
        const int j  = oo >> 2;
        const int cc = oo & 3;
        float dir = ((const float*)&s_dirp[0][r * 2 + j])[cc]
                  + ((const float*)&s_dirp[1][r * 2 + j])[cc]
                  + ((const float*)&s_dirp[2][r * 2 + j])[cc]
                  + ((const float*)&s_dirp[3][r * 2 + j])[cc];
        const float* zp = s_z[r] + oo * 8;
        float pos = __expf(zp[0]) + 0.25f * __expf(zp[1])
                  + (1.0f / 9.0f) * __expf(zp[2]) + 0.0625f * __expf(zp[3]);
        float neg = __expf(zp[4]) + 0.25f * __expf(zp[5])
                  + (1.0f / 9.0f) * __expf(zp[6]) + 0.0625f * __expf(zp[7]);
        out[(rowbase + r) * ODIM + slice * 8 + oo] = dir + pos - neg;
    }
}

extern "C" void kernel_launch(void* const* d_in, const int* in_sizes, int n_in,
                              void* d_out, int out_size, void* d_ws, size_t ws_size,
                              hipStream_t stream) {
    const float* x    = (const float*)d_in[0];
    const float* dtab = (const float*)d_in[1];
    const float* itab = (const float*)d_in[2];
    float* out = (float*)d_out;
    hipLaunchKernelGGL(abel_spline_kernel, dim3(BATCH / RPB * SLICES), dim3(TPB), 0, stream,
                       x, dtab, itab, out);
}

// Round 8
// 64.465 us; speedup vs baseline: 1.3168x; 1.1091x over previous
//
#include <hip/hip_runtime.h>

// ABELSpline: B=1024, D=128, DENSITY=259, ODIM=64, IDIM=512
// out[b,o] = direct[b,o] + sum_n c_n*(exp(z[b,8o+n]) - exp(z[b,8o+4+n])), c_n=(n+1)^-2
// direct[b,o] = sum_{d,k} w[b,d,k] * dtab[d*259 + p[b,d] + k, o]
// z[b,j]      = sum_{d,k} w[b,d,k] * itab[d*259 + p[b,d] + k, j]
// p = floor(256*x); p+3 <= 258 so the reference's mod never wraps.
//
// Round 7: EXACT round-3 structure (62.8us best: RPB=8, TPB=256, [r][d] LDS,
// indirect loop with 2 gathers in flight + unroll 2 -> FETCH 52MB) with ONLY
// the direct phase re-mapped. Lesson from R4/R5/R6: any change to the indirect
// loop's pacing (MLP depth, LDS transpose, row split) triples L2-miss traffic
// (drift across the ~128 resident blocks/XCD sharing the 66KB/dim stripe).
// Direct phase: lane = dd(3b)|qD(2b)|jD(1b); lane-varying LDS index is d
// (16B stride -> 32 banks for w, 8 broadcast addrs for base) -- the pattern
// measured conflict-free (8K) in rounds 4/5. Wave owns its 2 rows end-to-end;
// epilogue needs no cross-wave partials.

constexpr int BATCH = 1024;
constexpr int DIN = 128;
constexpr int DENSITY = 259;
constexpr int ODIM = 64;
constexpr int IDIM = 512;
constexpr int SLICES = 8;           // = #XCDs; 8 outputs / 64 indirect cols each
constexpr int RPB = 8;              // batch rows per block
constexpr int TPB = 256;            // 4 waves; wave wv owns rows 2wv, 2wv+1

__device__ __forceinline__ void fma4(float4& a, float s, const float4 v) {
    a.x = fmaf(s, v.x, a.x);
    a.y = fmaf(s, v.y, a.y);
    a.z = fmaf(s, v.z, a.z);
    a.w = fmaf(s, v.w, a.w);
}

__device__ __forceinline__ void add4(float4& a, const float4 t) {
    a.x += t.x; a.y += t.y; a.z += t.z; a.w += t.w;
}

__device__ __forceinline__ float4 shfl_xor4(float4 v, int m) {
    return make_float4(__shfl_xor(v.x, m), __shfl_xor(v.y, m),
                       __shfl_xor(v.z, m), __shfl_xor(v.w, m));
}

__global__ __launch_bounds__(TPB) void abel_spline_kernel(
    const float* __restrict__ x,
    const float* __restrict__ dtab,
    const float* __restrict__ itab,
    float* __restrict__ out)
{
    __shared__ float4 s_w[RPB][DIN];     // spline weights per (row, dim)
    __shared__ int    s_base[RPB][DIN];  // d*259 + floor(256*x)
    __shared__ float  s_z[RPB][64];      // z for this slice's 64 indirect cols
    __shared__ float4 s_dir4[RPB][2];    // direct sums (8 cols = 2 float4) per row

    const int bid   = blockIdx.x;
    const int slice = bid & (SLICES - 1);   // round-robin -> XCD-pinned stripe
    const int chunk = bid >> 3;             // 0..127
    const int tid   = threadIdx.x;
    const int wv    = tid >> 6;             // 0..3
    const int lane  = tid & 63;
    const int rowbase = chunk * RPB;

    // ---- phase 1: weights + base row index for all (r,d) pairs (identical to R3)
    for (int i = tid; i < RPB * DIN; i += TPB) {
        const int r = i >> 7;       // 0..7
        const int d = i & 127;
        float xv = x[(rowbase + r) * DIN + d];
        float t  = xv * 256.0f;     // scale = DENSITY-3 = 256
        float fl = floorf(t);
        float f  = t - fl;
        float f2 = f * f;
        float f3 = f2 * f;
        float om = 1.0f - f;
        float w0 = om * om * om * (1.0f / 6.0f);
        float w1 = (3.0f * f3 - 6.0f * f2 + 4.0f) * (1.0f / 6.0f);
        float w2 = (-3.0f * f3 + 3.0f * f2 + 3.0f * f + 1.0f) * (1.0f / 6.0f);
        float w3 = f3 * (1.0f / 6.0f);
        s_w[r][d]    = make_float4(w0, w1, w2, w3);
        s_base[r][d] = d * DENSITY + (int)fl;
    }
    __syncthreads();

    // ---- phase 2a: indirect stripe (identical to R3's: 2 gathers in flight).
    // lane = knot q (lane>>4) x col-quad c4 (lane&15).
    const int q  = lane >> 4;
    const int c4 = lane & 15;
    const float* __restrict__ itL = itab + (size_t)q * IDIM + slice * 64 + c4 * 4;
    const int r0 = 2 * wv, r1 = 2 * wv + 1;

    float4 a0 = make_float4(0.f, 0.f, 0.f, 0.f);
    float4 a1 = make_float4(0.f, 0.f, 0.f, 0.f);

    #pragma unroll 2
    for (int d = 0; d < DIN; ++d) {
        const int   b0 = s_base[r0][d];
        const int   b1 = s_base[r1][d];
        const float w0 = ((const float*)&s_w[r0][d])[q];
        const float w1 = ((const float*)&s_w[r1][d])[q];
        float4 v0 = *(const float4*)(itL + (size_t)b0 * IDIM);
        float4 v1 = *(const float4*)(itL + (size_t)b1 * IDIM);
        fma4(a0, w0, v0);
        fma4(a1, w1, v1);
    }
    // reduce over knot q (lane bits 4-5)
    add4(a0, shfl_xor4(a0, 16));
    add4(a0, shfl_xor4(a0, 32));
    add4(a1, shfl_xor4(a1, 16));
    add4(a1, shfl_xor4(a1, 32));
    if (q == 0) {
        reinterpret_cast<float4*>(s_z[r0])[c4] = a0;
        reinterpret_cast<float4*>(s_z[r1])[c4] = a1;
    }

    // ---- phase 2b: direct stripe (8 cols), wave owns rows r0,r1.
    // lane = dd(3b, bits 3-5) | qD(2b, bits 1-2) | jD(1b, bit 0); 8 dims/iter.
    // LDS: s_base[r][d0+dd] -> 8 broadcast addrs (stride 4B, 8 banks);
    //      s_w[r][d0+dd][qD] -> word idx 4*dd+qD -> 32 distinct banks. Clean.
    const int dd = lane >> 3;
    const int qD = (lane >> 1) & 3;
    const int jD = lane & 1;
    const float* __restrict__ dtL = dtab + (size_t)qD * ODIM + slice * 8 + jD * 4;

    float4 aD0 = make_float4(0.f, 0.f, 0.f, 0.f);
    float4 aD1 = make_float4(0.f, 0.f, 0.f, 0.f);
    #pragma unroll 2
    for (int d0 = 0; d0 < DIN; d0 += 8) {
        const int   dA  = d0 + dd;
        const int   bD0 = s_base[r0][dA];
        const int   bD1 = s_base[r1][dA];
        const float wD0 = ((const float*)&s_w[r0][dA])[qD];
        const float wD1 = ((const float*)&s_w[r1][dA])[qD];
        float4 u0 = *(const float4*)(dtL + (size_t)bD0 * ODIM);
        float4 u1 = *(const float4*)(dtL + (size_t)bD1 * ODIM);
        fma4(aD0, wD0, u0);
        fma4(aD1, wD1, u1);
    }
    // reduce over qD and dd (lane bits 1-5); jD (bit 0) distinguishes col quads
    add4(aD0, shfl_xor4(aD0, 2));
    add4(aD0, shfl_xor4(aD0, 4));
    add4(aD0, shfl_xor4(aD0, 8));
    add4(aD0, shfl_xor4(aD0, 16));
    add4(aD0, shfl_xor4(aD0, 32));
    add4(aD1, shfl_xor4(aD1, 2));
    add4(aD1, shfl_xor4(aD1, 4));
    add4(aD1, shfl_xor4(aD1, 8));
    add4(aD1, shfl_xor4(aD1, 16));
    add4(aD1, shfl_xor4(aD1, 32));
    if (lane < 2) {                      // lane == jD
        s_dir4[r0][lane] = aD0;
        s_dir4[r1][lane] = aD1;
    }
    __syncthreads();

    // ---- phase 3: epilogue, 64 threads = 8 rows x 8 outputs of this slice
    if (tid < RPB * 8) {
        const int r  = tid >> 3;
        const int oo = tid & 7;
        float dir = ((const float*)&s_dir4[r][oo >> 2])[oo & 3];
        const float* zp = s_z[r] + oo * 8;
        float pos = __expf(zp[0]) + 0.25f * __expf(zp[1])
                  + (1.0f / 9.0f) * __expf(zp[2]) + 0.0625f * __expf(zp[3]);
        float neg = __expf(zp[4]) + 0.25f * __expf(zp[5])
                  + (1.0f / 9.0f) * __expf(zp[6]) + 0.0625f * __expf(zp[7]);
        out[(rowbase + r) * ODIM + slice * 8 + oo] = dir + pos - neg;
    }
}

extern "C" void kernel_launch(void* const* d_in, const int* in_sizes, int n_in,
                              void* d_out, int out_size, void* d_ws, size_t ws_size,
                              hipStream_t stream) {
    const float* x    = (const float*)d_in[0];
    const float* dtab = (const float*)d_in[1];
    const float* itab = (const float*)d_in[2];
    float* out = (float*)d_out;
    hipLaunchKernelGGL(abel_spline_kernel, dim3(BATCH / RPB * SLICES), dim3(TPB), 0, stream,
                       x, dtab, itab, out);
}

// Round 9
// 63.780 us; speedup vs baseline: 1.3309x; 1.0107x over previous
//
#include <hip/hip_runtime.h>

// ABELSpline: B=1024, D=128, DENSITY=259, ODIM=64, IDIM=512
// out[b,o] = direct[b,o] + sum_n c_n*(exp(z[b,8o+n]) - exp(z[b,8o+4+n])), c_n=(n+1)^-2
// direct[b,o] = sum_{d,k} w[b,d,k] * dtab[d*259 + p[b,d] + k, o]
// z[b,j]      = sum_{d,k} w[b,d,k] * itab[d*259 + p[b,d] + k, j]
// p = floor(256*x); p+3 <= 258 so the reference's mod never wraps.
//
// Round 8: per-call repack of both tables into SLICE-MAJOR BF16 in d_ws.
//  - per-XCD stripe 8.5MB -> 4.24MB (~L2-resident): refetch multiplier and
//    drift-sensitivity collapse (R3-R7: FETCH 52-135MB depending on pacing).
//  - indirect (row,dim) window becomes 512B CONTIGUOUS (adjacent table rows
//    adjacent in slice-major) = 1 wave-load, 8 lines (was 16). direct window
//    64B = 1 line (was ~8). L2-served bytes halve: ~0.66GB -> ~20us floor.
//  - bf16 quantization (RTN) adds ~1e-3 error vs 0.0388 threshold. Gather
//    pacing kept IDENTICAL to R3 (2 loads in flight, unroll 2, [r][d] LDS).
// Fallback to the fp32 R7 kernel if ws_size < 38.2MB.

constexpr int BATCH = 1024;
constexpr int DIN = 128;
constexpr int DENSITY = 259;
constexpr int ODIM = 64;
constexpr int IDIM = 512;
constexpr int SLICES = 8;           // = #XCDs; 8 outputs / 64 indirect cols each
constexpr int RPB = 8;              // batch rows per block
constexpr int TPB = 256;            // 4 waves; wave wv owns rows 2wv, 2wv+1
constexpr int ROWS = DIN * DENSITY; // 33152 table rows
constexpr size_t WSI_ELEMS = (size_t)SLICES * ROWS * 64;  // bf16 indirect repack
constexpr size_t WSD_ELEMS = (size_t)SLICES * ROWS * 8;   // bf16 direct repack
constexpr size_t WS_NEEDED = (WSI_ELEMS + WSD_ELEMS) * 2; // 38,191,104 B

__device__ __forceinline__ void fma4(float4& a, float s, const float4 v) {
    a.x = fmaf(s, v.x, a.x);
    a.y = fmaf(s, v.y, a.y);
    a.z = fmaf(s, v.z, a.z);
    a.w = fmaf(s, v.w, a.w);
}

__device__ __forceinline__ void add4(float4& a, const float4 t) {
    a.x += t.x; a.y += t.y; a.z += t.z; a.w += t.w;
}

__device__ __forceinline__ float4 shfl_xor4(float4 v, int m) {
    return make_float4(__shfl_xor(v.x, m), __shfl_xor(v.y, m),
                       __shfl_xor(v.z, m), __shfl_xor(v.w, m));
}

__device__ __forceinline__ float2 shfl_xor2(float2 v, int m) {
    return make_float2(__shfl_xor(v.x, m), __shfl_xor(v.y, m));
}

__device__ __forceinline__ unsigned bf16r(float f) {  // fp32 -> bf16 bits (RTN-even)
    unsigned u = __float_as_uint(f);
    return (u + 0x7fffu + ((u >> 16) & 1u)) >> 16;
}

// ---- repack kernel: both tables -> slice-major bf16 in ws.
// blocks [0, ROWS): itab row per block (256 thr x float2 = 512 cols).
// blocks [ROWS, ROWS + ROWS/8): dtab, 8 rows per block.
__global__ __launch_bounds__(256) void repack_kernel(
    const float* __restrict__ dtab,
    const float* __restrict__ itab,
    unsigned short* __restrict__ wsI,
    unsigned short* __restrict__ wsD)
{
    const int bid = blockIdx.x;
    const int t   = threadIdx.x;
    if (bid < ROWS) {
        const float2 v = *(const float2*)(itab + (size_t)bid * IDIM + 2 * t);
        const unsigned o = bf16r(v.x) | (bf16r(v.y) << 16);
        const int slice = t >> 5;          // col = 2t; slice = col/64
        const int c2    = t & 31;          // pair index within slice stripe
        ((unsigned*)wsI)[((size_t)slice * ROWS + bid) * 32 + c2] = o;
    } else {
        const int rb  = bid - ROWS;        // 0..ROWS/8-1
        const int row = rb * 8 + (t >> 5);
        const int tt  = t & 31;
        const float2 v = *(const float2*)(dtab + (size_t)row * ODIM + 2 * tt);
        const unsigned o = bf16r(v.x) | (bf16r(v.y) << 16);
        const int slice = tt >> 2;         // col = 2tt; slice = col/8
        const int j     = tt & 3;          // pair index within 8-col stripe
        ((unsigned*)wsD)[((size_t)slice * ROWS + row) * 4 + j] = o;
    }
}

// ---- main kernel, bf16 slice-major tables
__global__ __launch_bounds__(TPB) void abel_bf16_kernel(
    const float* __restrict__ x,
    const unsigned short* __restrict__ wsI,
    const unsigned short* __restrict__ wsD,
    float* __restrict__ out)
{
    __shared__ float4 s_w[RPB][DIN];     // spline weights per (row, dim)
    __shared__ int    s_base[RPB][DIN];  // d*259 + floor(256*x)
    __shared__ float  s_z[RPB][64];      // z for this slice's 64 indirect cols
    __shared__ float2 s_dir2[RPB][4];    // direct sums (8 cols = 4 float2) per row

    const int bid   = blockIdx.x;
    const int slice = bid & (SLICES - 1);   // round-robin -> XCD-pinned stripe
    const int chunk = bid >> 3;             // 0..127
    const int tid   = threadIdx.x;
    const int wv    = tid >> 6;             // 0..3
    const int lane  = tid & 63;
    const int rowbase = chunk * RPB;

    // ---- phase 1: weights + base row index for all (r,d) pairs
    for (int i = tid; i < RPB * DIN; i += TPB) {
        const int r = i >> 7;       // 0..7
        const int d = i & 127;
        float xv = x[(rowbase + r) * DIN + d];
        float t  = xv * 256.0f;     // scale = DENSITY-3 = 256
        float fl = floorf(t);
        float f  = t - fl;
        float f2 = f * f;
        float f3 = f2 * f;
        float om = 1.0f - f;
        float w0 = om * om * om * (1.0f / 6.0f);
        float w1 = (3.0f * f3 - 6.0f * f2 + 4.0f) * (1.0f / 6.0f);
        float w2 = (-3.0f * f3 + 3.0f * f2 + 3.0f * f + 1.0f) * (1.0f / 6.0f);
        float w3 = f3 * (1.0f / 6.0f);
        s_w[r][d]    = make_float4(w0, w1, w2, w3);
        s_base[r][d] = d * DENSITY + (int)fl;
    }
    __syncthreads();

    // ---- phase 2a: indirect stripe, 2 rows per wave, R3 pacing (2 loads in flight).
    // Window for (row,dim) = 512B contiguous (4 table rows x 128B, slice-major).
    // lane = knot q (lane>>4) x col-quad c4 (lane&15): lane reads uint2 = 4 bf16.
    const int q  = lane >> 4;
    const int c4 = lane & 15;
    const uint2* __restrict__ itL =
        (const uint2*)wsI + ((size_t)slice * ROWS) * 16 + lane;  // 16 uint2 per row
    const int r0 = 2 * wv, r1 = 2 * wv + 1;

    float4 a0 = make_float4(0.f, 0.f, 0.f, 0.f);
    float4 a1 = make_float4(0.f, 0.f, 0.f, 0.f);

    #pragma unroll 2
    for (int d = 0; d < DIN; ++d) {
        const int   b0 = s_base[r0][d];
        const int   b1 = s_base[r1][d];
        const float w0 = ((const float*)&s_w[r0][d])[q];
        const float w1 = ((const float*)&s_w[r1][d])[q];
        const uint2 u0 = itL[(size_t)b0 * 16];
        const uint2 u1 = itL[(size_t)b1 * 16];
        float4 v0 = make_float4(__uint_as_float(u0.x << 16),
                                __uint_as_float(u0.x & 0xffff0000u),
                                __uint_as_float(u0.y << 16),
                                __uint_as_float(u0.y & 0xffff0000u));
        float4 v1 = make_float4(__uint_as_float(u1.x << 16),
                                __uint_as_float(u1.x & 0xffff0000u),
                                __uint_as_float(u1.y << 16),
                                __uint_as_float(u1.y & 0xffff0000u));
        fma4(a0, w0, v0);
        fma4(a1, w1, v1);
    }
    // reduce over knot q (lane bits 4-5)
    add4(a0, shfl_xor4(a0, 16));
    add4(a0, shfl_xor4(a0, 32));
    add4(a1, shfl_xor4(a1, 16));
    add4(a1, shfl_xor4(a1, 32));
    if (q == 0) {
        reinterpret_cast<float4*>(s_z[r0])[c4] = a0;
        reinterpret_cast<float4*>(s_z[r1])[c4] = a1;
    }

    // ---- phase 2b: direct stripe (8 cols), wave owns rows r0,r1.
    // lane = dd(2b, bits 4-5: 4 dims/iter) | qd(2b, bits 2-3) | jj(2b, bits 0-1).
    // Window for (row,dim) = 64B contiguous (4 rows x 16B, slice-major bf16).
    // LDS: s_base[r][d0+dd] -> 4 words, broadcast; s_w word idx (d0+dd)*4+qd ->
    // 16 consecutive words, 4-way broadcast. Conflict-free.
    const int dd = lane >> 4;
    const int qd = (lane >> 2) & 3;
    const int jj = lane & 3;
    const unsigned* __restrict__ dtL =
        (const unsigned*)wsD + ((size_t)slice * ROWS) * 4 + qd * 4 + jj;

    float2 aD0 = make_float2(0.f, 0.f);
    float2 aD1 = make_float2(0.f, 0.f);
    #pragma unroll 2
    for (int d0 = 0; d0 < DIN; d0 += 4) {
        const int   dA  = d0 + dd;
        const int   bD0 = s_base[r0][dA];
        const int   bD1 = s_base[r1][dA];
        const float wD0 = ((const float*)&s_w[r0][dA])[qd];
        const float wD1 = ((const float*)&s_w[r1][dA])[qd];
        const unsigned g0 = dtL[(size_t)bD0 * 4];
        const unsigned g1 = dtL[(size_t)bD1 * 4];
        aD0.x = fmaf(wD0, __uint_as_float(g0 << 16), aD0.x);
        aD0.y = fmaf(wD0, __uint_as_float(g0 & 0xffff0000u), aD0.y);
        aD1.x = fmaf(wD1, __uint_as_float(g1 << 16), aD1.x);
        aD1.y = fmaf(wD1, __uint_as_float(g1 & 0xffff0000u), aD1.y);
    }
    // reduce over qd (bits 2-3) and dd (bits 4-5); jj (bits 0-1) = col pair
    aD0 = make_float2(aD0.x + __shfl_xor(aD0.x, 4), aD0.y + __shfl_xor(aD0.y, 4));
    aD0 = make_float2(aD0.x + __shfl_xor(aD0.x, 8), aD0.y + __shfl_xor(aD0.y, 8));
    aD0 = make_float2(aD0.x + __shfl_xor(aD0.x, 16), aD0.y + __shfl_xor(aD0.y, 16));
    aD0 = make_float2(aD0.x + __shfl_xor(aD0.x, 32), aD0.y + __shfl_xor(aD0.y, 32));
    aD1 = make_float2(aD1.x + __shfl_xor(aD1.x, 4), aD1.y + __shfl_xor(aD1.y, 4));
    aD1 = make_float2(aD1.x + __shfl_xor(aD1.x, 8), aD1.y + __shfl_xor(aD1.y, 8));
    aD1 = make_float2(aD1.x + __shfl_xor(aD1.x, 16), aD1.y + __shfl_xor(aD1.y, 16));
    aD1 = make_float2(aD1.x + __shfl_xor(aD1.x, 32), aD1.y + __shfl_xor(aD1.y, 32));
    if (lane < 4) {                      // lane == jj
        s_dir2[r0][lane] = aD0;
        s_dir2[r1][lane] = aD1;
    }
    __syncthreads();

    // ---- phase 3: epilogue, 64 threads = 8 rows x 8 outputs of this slice
    if (tid < RPB * 8) {
        const int r  = tid >> 3;
        const int oo = tid & 7;
        float dir = ((const float*)&s_dir2[r][0])[oo];
        const float* zp = s_z[r] + oo * 8;
        float pos = __expf(zp[0]) + 0.25f * __expf(zp[1])
                  + (1.0f / 9.0f) * __expf(zp[2]) + 0.0625f * __expf(zp[3]);
        float neg = __expf(zp[4]) + 0.25f * __expf(zp[5])
                  + (1.0f / 9.0f) * __expf(zp[6]) + 0.0625f * __expf(zp[7]);
        out[(rowbase + r) * ODIM + slice * 8 + oo] = dir + pos - neg;
    }
}

// ---- fp32 fallback (round-7 kernel) for ws_size < WS_NEEDED
__global__ __launch_bounds__(TPB) void abel_fp32_kernel(
    const float* __restrict__ x,
    const float* __restrict__ dtab,
    const float* __restrict__ itab,
    float* __restrict__ out)
{
    __shared__ float4 s_w[RPB][DIN];
    __shared__ int    s_base[RPB][DIN];
    __shared__ float  s_z[RPB][64];
    __shared__ float4 s_dir4[RPB][2];

    const int bid   = blockIdx.x;
    const int slice = bid & (SLICES - 1);
    const int chunk = bid >> 3;
    const int tid   = threadIdx.x;
    const int wv    = tid >> 6;
    const int lane  = tid & 63;
    const int rowbase = chunk * RPB;

    for (int i = tid; i < RPB * DIN; i += TPB) {
        const int r = i >> 7;
        const int d = i & 127;
        float xv = x[(rowbase + r) * DIN + d];
        float t  = xv * 256.0f;
        float fl = floorf(t);
        float f  = t - fl;
        float f2 = f * f;
        float f3 = f2 * f;
        float om = 1.0f - f;
        float w0 = om * om * om * (1.0f / 6.0f);
        float w1 = (3.0f * f3 - 6.0f * f2 + 4.0f) * (1.0f / 6.0f);
        float w2 = (-3.0f * f3 + 3.0f * f2 + 3.0f * f + 1.0f) * (1.0f / 6.0f);
        float w3 = f3 * (1.0f / 6.0f);
        s_w[r][d]    = make_float4(w0, w1, w2, w3);
        s_base[r][d] = d * DENSITY + (int)fl;
    }
    __syncthreads();

    const int q  = lane >> 4;
    const int c4 = lane & 15;
    const float* __restrict__ itL = itab + (size_t)q * IDIM + slice * 64 + c4 * 4;
    const int r0 = 2 * wv, r1 = 2 * wv + 1;

    float4 a0 = make_float4(0.f, 0.f, 0.f, 0.f);
    float4 a1 = make_float4(0.f, 0.f, 0.f, 0.f);
    #pragma unroll 2
    for (int d = 0; d < DIN; ++d) {
        const int   b0 = s_base[r0][d];
        const int   b1 = s_base[r1][d];
        const float w0 = ((const float*)&s_w[r0][d])[q];
        const float w1 = ((const float*)&s_w[r1][d])[q];
        float4 v0 = *(const float4*)(itL + (size_t)b0 * IDIM);
        float4 v1 = *(const float4*)(itL + (size_t)b1 * IDIM);
        fma4(a0, w0, v0);
        fma4(a1, w1, v1);
    }
    add4(a0, shfl_xor4(a0, 16));
    add4(a0, shfl_xor4(a0, 32));
    add4(a1, shfl_xor4(a1, 16));
    add4(a1, shfl_xor4(a1, 32));
    if (q == 0) {
        reinterpret_cast<float4*>(s_z[r0])[c4] = a0;
        reinterpret_cast<float4*>(s_z[r1])[c4] = a1;
    }

    const int dd = lane >> 3;
    const int qD = (lane >> 1) & 3;
    const int jD = lane & 1;
    const float* __restrict__ dtL = dtab + (size_t)qD * ODIM + slice * 8 + jD * 4;

    float4 aD0 = make_float4(0.f, 0.f, 0.f, 0.f);
    float4 aD1 = make_float4(0.f, 0.f, 0.f, 0.f);
    #pragma unroll 2
    for (int d0 = 0; d0 < DIN; d0 += 8) {
        const int   dA  = d0 + dd;
        const int   bD0 = s_base[r0][dA];
        const int   bD1 = s_base[r1][dA];
        const float wD0 = ((const float*)&s_w[r0][dA])[qD];
        const float wD1 = ((const float*)&s_w[r1][dA])[qD];
        float4 u0 = *(const float4*)(dtL + (size_t)bD0 * ODIM);
        float4 u1 = *(const float4*)(dtL + (size_t)bD1 * ODIM);
        fma4(aD0, wD0, u0);
        fma4(aD1, wD1, u1);
    }
    add4(aD0, shfl_xor4(aD0, 2));
    add4(aD0, shfl_xor4(aD0, 4));
    add4(aD0, shfl_xor4(aD0, 8));
    add4(aD0, shfl_xor4(aD0, 16));
    add4(aD0, shfl_xor4(aD0, 32));
    add4(aD1, shfl_xor4(aD1, 2));
    add4(aD1, shfl_xor4(aD1, 4));
    add4(aD1, shfl_xor4(aD1, 8));
    add4(aD1, shfl_xor4(aD1, 16));
    add4(aD1, shfl_xor4(aD1, 32));
    if (lane < 2) {
        s_dir4[r0][lane] = aD0;
        s_dir4[r1][lane] = aD1;
    }
    __syncthreads();

    if (tid < RPB * 8) {
        const int r  = tid >> 3;
        const int oo = tid & 7;
        float dir = ((const float*)&s_dir4[r][oo >> 2])[oo & 3];
        const float* zp = s_z[r] + oo * 8;
        float pos = __expf(zp[0]) + 0.25f * __expf(zp[1])
                  + (1.0f / 9.0f) * __expf(zp[2]) + 0.0625f * __expf(zp[3]);
        float neg = __expf(zp[4]) + 0.25f * __expf(zp[5])
                  + (1.0f / 9.0f) * __expf(zp[6]) + 0.0625f * __expf(zp[7]);
        out[(rowbase + r) * ODIM + slice * 8 + oo] = dir + pos - neg;
    }
}

extern "C" void kernel_launch(void* const* d_in, const int* in_sizes, int n_in,
                              void* d_out, int out_size, void* d_ws, size_t ws_size,
                              hipStream_t stream) {
    const float* x    = (const float*)d_in[0];
    const float* dtab = (const float*)d_in[1];
    const float* itab = (const float*)d_in[2];
    float* out = (float*)d_out;

    if (ws_size >= WS_NEEDED) {
        unsigned short* wsI = (unsigned short*)d_ws;
        unsigned short* wsD = wsI + WSI_ELEMS;
        hipLaunchKernelGGL(repack_kernel, dim3(ROWS + ROWS / 8), dim3(256), 0, stream,
                           dtab, itab, wsI, wsD);
        hipLaunchKernelGGL(abel_bf16_kernel, dim3(BATCH / RPB * SLICES), dim3(TPB), 0, stream,
                           x, wsI, wsD, out);
    } else {
        hipLaunchKernelGGL(abel_fp32_kernel, dim3(BATCH / RPB * SLICES), dim3(TPB), 0, stream,
                           x, dtab, itab, out);
    }
}

// Round 10
// 61.321 us; speedup vs baseline: 1.3843x; 1.0401x over previous
//
#include <hip/hip_runtime.h>

// ABELSpline: B=1024, D=128, DENSITY=259, ODIM=64, IDIM=512
// out[b,o] = direct[b,o] + sum_n c_n*(exp(z[b,8o+n]) - exp(z[b,8o+4+n])), c_n=(n+1)^-2
// direct[b,o] = sum_{d,k} w[b,d,k] * dtab[d*259 + p[b,d] + k, o]
// z[b,j]      = sum_{d,k} w[b,d,k] * itab[d*259 + p[b,d] + k, j]
// p = floor(256*x); p+3 <= 258 so the reference's mod never wraps.
//
// Round 9: bf16 slice-major repack (R8: stripe L2-resident, main FETCH 20.7MB)
// + occupancy fix now that pacing no longer matters:
//  - TPB 256->512: 8 waves/block, each wave = 2 batch rows x 64-dim HALF
//    (half = wv>>2). Grid 1024 blocks x 8 waves = 32 waves/CU cap (was 16).
//    Partials for the two halves reduced in the epilogue.
//  - 32-bit gather offsets off a wave-uniform base -> saddr-form global_load
//    (saves ~3 VALU per gather vs 64-bit per-lane pointer arithmetic).
//  - repack kernel vectorized to float4 reads.

constexpr int BATCH = 1024;
constexpr int DIN = 128;
constexpr int DENSITY = 259;
constexpr int ODIM = 64;
constexpr int IDIM = 512;
constexpr int SLICES = 8;           // = #XCDs; 8 outputs / 64 indirect cols each
constexpr int RPB = 8;              // batch rows per block
constexpr int TPB = 512;            // 8 waves; wave wv: rows 2*(wv&3), +1; dims (wv>>2)*64..+63
constexpr int ROWS = DIN * DENSITY; // 33152 table rows
constexpr size_t WSI_ELEMS = (size_t)SLICES * ROWS * 64;  // bf16 indirect repack
constexpr size_t WSD_ELEMS = (size_t)SLICES * ROWS * 8;   // bf16 direct repack
constexpr size_t WS_NEEDED = (WSI_ELEMS + WSD_ELEMS) * 2; // 38,191,104 B

__device__ __forceinline__ void fma4(float4& a, float s, const float4 v) {
    a.x = fmaf(s, v.x, a.x);
    a.y = fmaf(s, v.y, a.y);
    a.z = fmaf(s, v.z, a.z);
    a.w = fmaf(s, v.w, a.w);
}

__device__ __forceinline__ void add4(float4& a, const float4 t) {
    a.x += t.x; a.y += t.y; a.z += t.z; a.w += t.w;
}

__device__ __forceinline__ float4 shfl_xor4(float4 v, int m) {
    return make_float4(__shfl_xor(v.x, m), __shfl_xor(v.y, m),
                       __shfl_xor(v.z, m), __shfl_xor(v.w, m));
}

__device__ __forceinline__ unsigned bf16r(float f) {  // fp32 -> bf16 bits (RTN-even)
    unsigned u = __float_as_uint(f);
    return (u + 0x7fffu + ((u >> 16) & 1u)) >> 16;
}

// ---- repack kernel: both tables -> slice-major bf16 in ws (float4 reads).
// blocks [0, ROWS/2): itab, 2 rows per block (128 thr/row x float4).
// blocks [ROWS/2, ROWS/2 + ROWS/16): dtab, 16 rows per block (16 thr/row x float4).
__global__ __launch_bounds__(256) void repack_kernel(
    const float* __restrict__ dtab,
    const float* __restrict__ itab,
    unsigned short* __restrict__ wsI,
    unsigned short* __restrict__ wsD)
{
    const int bid = blockIdx.x;
    const int t   = threadIdx.x;
    if (bid < ROWS / 2) {
        const int row  = bid * 2 + (t >> 7);
        const int t128 = t & 127;
        const float4 v = *(const float4*)(itab + (size_t)row * IDIM + t128 * 4);
        const unsigned o0 = bf16r(v.x) | (bf16r(v.y) << 16);
        const unsigned o1 = bf16r(v.z) | (bf16r(v.w) << 16);
        const int slice = t128 >> 4;       // col = 4*t128; slice = col/64
        const int c4    = t128 & 15;       // quad index within 64-col stripe
        ((uint2*)wsI)[((size_t)slice * ROWS + row) * 16 + c4] = make_uint2(o0, o1);
    } else {
        const int rb  = bid - ROWS / 2;
        const int row = rb * 16 + (t >> 4);
        const int j   = t & 15;
        const float4 v = *(const float4*)(dtab + (size_t)row * ODIM + j * 4);
        const unsigned o0 = bf16r(v.x) | (bf16r(v.y) << 16);
        const unsigned o1 = bf16r(v.z) | (bf16r(v.w) << 16);
        const int slice = j >> 1;          // col = 4j; slice = col/8
        const int jj2   = j & 1;           // uint2 half within 8-col stripe
        ((uint2*)wsD)[((size_t)slice * ROWS + row) * 2 + jj2] = make_uint2(o0, o1);
    }
}

// ---- main kernel, bf16 slice-major tables, 8 waves (2 rows x 64-dim half each)
__global__ __launch_bounds__(TPB) void abel_bf16_kernel(
    const float* __restrict__ x,
    const unsigned short* __restrict__ wsI,
    const unsigned short* __restrict__ wsD,
    float* __restrict__ out)
{
    __shared__ float4 s_w[RPB][DIN];        // spline weights per (row, dim)
    __shared__ int    s_base[RPB][DIN];     // d*259 + floor(256*x)
    __shared__ float  s_zp[2][RPB][64];     // per-half indirect partials
    __shared__ float2 s_dp[2][RPB][4];      // per-half direct partials (8 cols)

    const int bid   = blockIdx.x;
    const int slice = bid & (SLICES - 1);   // round-robin -> XCD-pinned stripe
    const int chunk = bid >> 3;             // 0..127
    const int tid   = threadIdx.x;
    const int wv    = tid >> 6;             // 0..7
    const int half  = wv >> 2;              // dim half: 0 or 1
    const int wp    = wv & 3;               // row-pair index
    const int lane  = tid & 63;
    const int rowbase = chunk * RPB;
    const int r0 = 2 * wp, r1 = 2 * wp + 1;
    const int dBeg = half * 64;

    // ---- phase 1: weights + base row index for all (r,d) pairs (2 iters)
    for (int i = tid; i < RPB * DIN; i += TPB) {
        const int r = i >> 7;       // 0..7
        const int d = i & 127;
        float xv = x[(rowbase + r) * DIN + d];
        float t  = xv * 256.0f;     // scale = DENSITY-3 = 256
        float fl = floorf(t);
        float f  = t - fl;
        float f2 = f * f;
        float f3 = f2 * f;
        float om = 1.0f - f;
        float w0 = om * om * om * (1.0f / 6.0f);
        float w1 = (3.0f * f3 - 6.0f * f2 + 4.0f) * (1.0f / 6.0f);
        float w2 = (-3.0f * f3 + 3.0f * f2 + 3.0f * f + 1.0f) * (1.0f / 6.0f);
        float w3 = f3 * (1.0f / 6.0f);
        s_w[r][d]    = make_float4(w0, w1, w2, w3);
        s_base[r][d] = d * DENSITY + (int)fl;
    }
    __syncthreads();

    // ---- phase 2a: indirect stripe. lane = knot q (lane>>4) x col-quad c4 (lane&15).
    // Window = 512B contiguous; 32-bit offsets off wave-uniform base (saddr form).
    const int q  = lane >> 4;
    const int c4 = lane & 15;
    const uint2* __restrict__ itS = (const uint2*)wsI + (size_t)slice * ROWS * 16;

    float4 a0 = make_float4(0.f, 0.f, 0.f, 0.f);
    float4 a1 = make_float4(0.f, 0.f, 0.f, 0.f);

    #pragma unroll 2
    for (int d = dBeg; d < dBeg + 64; ++d) {
        const int   b0 = s_base[r0][d];
        const int   b1 = s_base[r1][d];
        const float w0 = ((const float*)&s_w[r0][d])[q];
        const float w1 = ((const float*)&s_w[r1][d])[q];
        const uint2 u0 = itS[b0 * 16 + lane];   // row b0+q, quad c4
        const uint2 u1 = itS[b1 * 16 + lane];
        float4 v0 = make_float4(__uint_as_float(u0.x << 16),
                                __uint_as_float(u0.x & 0xffff0000u),
                                __uint_as_float(u0.y << 16),
                                __uint_as_float(u0.y & 0xffff0000u));
        float4 v1 = make_float4(__uint_as_float(u1.x << 16),
                                __uint_as_float(u1.x & 0xffff0000u),
                                __uint_as_float(u1.y << 16),
                                __uint_as_float(u1.y & 0xffff0000u));
        fma4(a0, w0, v0);
        fma4(a1, w1, v1);
    }
    // reduce over knot q (lane bits 4-5)
    add4(a0, shfl_xor4(a0, 16));
    add4(a0, shfl_xor4(a0, 32));
    add4(a1, shfl_xor4(a1, 16));
    add4(a1, shfl_xor4(a1, 32));
    if (q == 0) {
        reinterpret_cast<float4*>(s_zp[half][r0])[c4] = a0;
        reinterpret_cast<float4*>(s_zp[half][r1])[c4] = a1;
    }

    // ---- phase 2b: direct stripe (8 cols), wave owns rows r0,r1 for its dim half.
    // lane = dd(2b, bits 4-5: 4 dims/iter) | qd(2b, bits 2-3: knot) | jj(2b, bits 0-1).
    const int dd = lane >> 4;
    const int qd = (lane >> 2) & 3;
    const int jj = lane & 3;
    const unsigned* __restrict__ dtS = (const unsigned*)wsD + (size_t)slice * ROWS * 4;
    const int dOff = qd * 4 + jj;

    float2 aD0 = make_float2(0.f, 0.f);
    float2 aD1 = make_float2(0.f, 0.f);
    #pragma unroll 2
    for (int d0 = dBeg; d0 < dBeg + 64; d0 += 4) {
        const int   dA  = d0 + dd;
        const int   bD0 = s_base[r0][dA];
        const int   bD1 = s_base[r1][dA];
        const float wD0 = ((const float*)&s_w[r0][dA])[qd];
        const float wD1 = ((const float*)&s_w[r1][dA])[qd];
        const unsigned g0 = dtS[bD0 * 4 + dOff];   // row bD0+qd, uint jj
        const unsigned g1 = dtS[bD1 * 4 + dOff];
        aD0.x = fmaf(wD0, __uint_as_float(g0 << 16), aD0.x);
        aD0.y = fmaf(wD0, __uint_as_float(g0 & 0xffff0000u), aD0.y);
        aD1.x = fmaf(wD1, __uint_as_float(g1 << 16), aD1.x);
        aD1.y = fmaf(wD1, __uint_as_float(g1 & 0xffff0000u), aD1.y);
    }
    // reduce over qd (bits 2-3) and dd (bits 4-5); jj (bits 0-1) = col pair
    aD0 = make_float2(aD0.x + __shfl_xor(aD0.x, 4), aD0.y + __shfl_xor(aD0.y, 4));
    aD0 = make_float2(aD0.x + __shfl_xor(aD0.x, 8), aD0.y + __shfl_xor(aD0.y, 8));
    aD0 = make_float2(aD0.x + __shfl_xor(aD0.x, 16), aD0.y + __shfl_xor(aD0.y, 16));
    aD0 = make_float2(aD0.x + __shfl_xor(aD0.x, 32), aD0.y + __shfl_xor(aD0.y, 32));
    aD1 = make_float2(aD1.x + __shfl_xor(aD1.x, 4), aD1.y + __shfl_xor(aD1.y, 4));
    aD1 = make_float2(aD1.x + __shfl_xor(aD1.x, 8), aD1.y + __shfl_xor(aD1.y, 8));
    aD1 = make_float2(aD1.x + __shfl_xor(aD1.x, 16), aD1.y + __shfl_xor(aD1.y, 16));
    aD1 = make_float2(aD1.x + __shfl_xor(aD1.x, 32), aD1.y + __shfl_xor(aD1.y, 32));
    if (lane < 4) {                      // lane == jj
        s_dp[half][r0][lane] = aD0;
        s_dp[half][r1][lane] = aD1;
    }
    __syncthreads();

    // ---- phase 3: epilogue, 64 threads = 8 rows x 8 outputs; sum the two halves
    if (tid < RPB * 8) {
        const int r  = tid >> 3;
        const int oo = tid & 7;
        float dir = ((const float*)&s_dp[0][r][0])[oo]
                  + ((const float*)&s_dp[1][r][0])[oo];
        const float* z0 = s_zp[0][r] + oo * 8;
        const float* z1 = s_zp[1][r] + oo * 8;
        float pos = __expf(z0[0] + z1[0]) + 0.25f * __expf(z0[1] + z1[1])
                  + (1.0f / 9.0f) * __expf(z0[2] + z1[2]) + 0.0625f * __expf(z0[3] + z1[3]);
        float neg = __expf(z0[4] + z1[4]) + 0.25f * __expf(z0[5] + z1[5])
                  + (1.0f / 9.0f) * __expf(z0[6] + z1[6]) + 0.0625f * __expf(z0[7] + z1[7]);
        out[(rowbase + r) * ODIM + slice * 8 + oo] = dir + pos - neg;
    }
}

// ---- fp32 fallback (round-7 kernel) for ws_size < WS_NEEDED
__global__ __launch_bounds__(256) void abel_fp32_kernel(
    const float* __restrict__ x,
    const float* __restrict__ dtab,
    const float* __restrict__ itab,
    float* __restrict__ out)
{
    __shared__ float4 s_w[RPB][DIN];
    __shared__ int    s_base[RPB][DIN];
    __shared__ float  s_z[RPB][64];
    __shared__ float4 s_dir4[RPB][2];

    const int bid   = blockIdx.x;
    const int slice = bid & (SLICES - 1);
    const int chunk = bid >> 3;
    const int tid   = threadIdx.x;
    const int wv    = tid >> 6;
    const int lane  = tid & 63;
    const int rowbase = chunk * RPB;

    for (int i = tid; i < RPB * DIN; i += 256) {
        const int r = i >> 7;
        const int d = i & 127;
        float xv = x[(rowbase + r) * DIN + d];
        float t  = xv * 256.0f;
        float fl = floorf(t);
        float f  = t - fl;
        float f2 = f * f;
        float f3 = f2 * f;
        float om = 1.0f - f;
        float w0 = om * om * om * (1.0f / 6.0f);
        float w1 = (3.0f * f3 - 6.0f * f2 + 4.0f) * (1.0f / 6.0f);
        float w2 = (-3.0f * f3 + 3.0f * f2 + 3.0f * f + 1.0f) * (1.0f / 6.0f);
        float w3 = f3 * (1.0f / 6.0f);
        s_w[r][d]    = make_float4(w0, w1, w2, w3);
        s_base[r][d] = d * DENSITY + (int)fl;
    }
    __syncthreads();

    const int q  = lane >> 4;
    const int c4 = lane & 15;
    const float* __restrict__ itL = itab + (size_t)q * IDIM + slice * 64 + c4 * 4;
    const int r0 = 2 * wv, r1 = 2 * wv + 1;

    float4 a0 = make_float4(0.f, 0.f, 0.f, 0.f);
    float4 a1 = make_float4(0.f, 0.f, 0.f, 0.f);
    #pragma unroll 2
    for (int d = 0; d < DIN; ++d) {
        const int   b0 = s_base[r0][d];
        const int   b1 = s_base[r1][d];
        const float w0 = ((const float*)&s_w[r0][d])[q];
        const float w1 = ((const float*)&s_w[r1][d])[q];
        float4 v0 = *(const float4*)(itL + (size_t)b0 * IDIM);
        float4 v1 = *(const float4*)(itL + (size_t)b1 * IDIM);
        fma4(a0, w0, v0);
        fma4(a1, w1, v1);
    }
    add4(a0, shfl_xor4(a0, 16));
    add4(a0, shfl_xor4(a0, 32));
    add4(a1, shfl_xor4(a1, 16));
    add4(a1, shfl_xor4(a1, 32));
    if (q == 0) {
        reinterpret_cast<float4*>(s_z[r0])[c4] = a0;
        reinterpret_cast<float4*>(s_z[r1])[c4] = a1;
    }

    const int dd = lane >> 3;
    const int qD = (lane >> 1) & 3;
    const int jD = lane & 1;
    const float* __restrict__ dtL = dtab + (size_t)qD * ODIM + slice * 8 + jD * 4;

    float4 aD0 = make_float4(0.f, 0.f, 0.f, 0.f);
    float4 aD1 = make_float4(0.f, 0.f, 0.f, 0.f);
    #pragma unroll 2
    for (int d0 = 0; d0 < DIN; d0 += 8) {
        const int   dA  = d0 + dd;
        const int   bD0 = s_base[r0][dA];
        const int   bD1 = s_base[r1][dA];
        const float wD0 = ((const float*)&s_w[r0][dA])[qD];
        const float wD1 = ((const float*)&s_w[r1][dA])[qD];
        float4 u0 = *(const float4*)(dtL + (size_t)bD0 * ODIM);
        float4 u1 = *(const float4*)(dtL + (size_t)bD1 * ODIM);
        fma4(aD0, wD0, u0);
        fma4(aD1, wD1, u1);
    }
    add4(aD0, shfl_xor4(aD0, 2));
    add4(aD0, shfl_xor4(aD0, 4));
    add4(aD0, shfl_xor4(aD0, 8));
    add4(aD0, shfl_xor4(aD0, 16));
    add4(aD0, shfl_xor4(aD0, 32));
    add4(aD1, shfl_xor4(aD1, 2));
    add4(aD1, shfl_xor4(aD1, 4));
    add4(aD1, shfl_xor4(aD1, 8));
    add4(aD1, shfl_xor4(aD1, 16));
    add4(aD1, shfl_xor4(aD1, 32));
    if (lane < 2) {
        s_dir4[r0][lane] = aD0;
        s_dir4[r1][lane] = aD1;
    }
    __syncthreads();

    if (tid < RPB * 8) {
        const int r  = tid >> 3;
        const int oo = tid & 7;
        float dir = ((const float*)&s_dir4[r][oo >> 2])[oo & 3];
        const float* zp = s_z[r] + oo * 8;
        float pos = __expf(zp[0]) + 0.25f * __expf(zp[1])
                  + (1.0f / 9.0f) * __expf(zp[2]) + 0.0625f * __expf(zp[3]);
        float neg = __expf(zp[4]) + 0.25f * __expf(zp[5])
                  + (1.0f / 9.0f) * __expf(zp[6]) + 0.0625f * __expf(zp[7]);
        out[(rowbase + r) * ODIM + slice * 8 + oo] = dir + pos - neg;
    }
}

extern "C" void kernel_launch(void* const* d_in, const int* in_sizes, int n_in,
                              void* d_out, int out_size, void* d_ws, size_t ws_size,
                              hipStream_t stream) {
    const float* x    = (const float*)d_in[0];
    const float* dtab = (const float*)d_in[1];
    const float* itab = (const float*)d_in[2];
    float* out = (float*)d_out;

    if (ws_size >= WS_NEEDED) {
        unsigned short* wsI = (unsigned short*)d_ws;
        unsigned short* wsD = wsI + WSI_ELEMS;
        hipLaunchKernelGGL(repack_kernel, dim3(ROWS / 2 + ROWS / 16), dim3(256), 0, stream,
                           dtab, itab, wsI, wsD);
        hipLaunchKernelGGL(abel_bf16_kernel, dim3(BATCH / RPB * SLICES), dim3(TPB), 0, stream,
                           x, wsI, wsD, out);
    } else {
        hipLaunchKernelGGL(abel_fp32_kernel, dim3(BATCH / RPB * SLICES), dim3(256), 0, stream,
                           x, dtab, itab, out);
    }
}

// Round 11
// 59.468 us; speedup vs baseline: 1.4274x; 1.0311x over previous
//
#include <hip/hip_runtime.h>

// ABELSpline: B=1024, D=128, DENSITY=259, ODIM=64, IDIM=512
// out[b,o] = direct[b,o] + sum_n c_n*(exp(z[b,8o+n]) - exp(z[b,8o+4+n])), c_n=(n+1)^-2
// direct[b,o] = sum_{d,k} w[b,d,k] * dtab[d*259 + p[b,d] + k, o]
// z[b,j]      = sum_{d,k} w[b,d,k] * itab[d*259 + p[b,d] + k, j]
// p = floor(256*x); p+3 <= 258 so the reference's mod never wraps.
//
// Round 10: fp16 slice-major repack (same bytes as bf16, MORE mantissa) and a
// leaner inner loop. R9 showed dur flat across 2x occupancy at 48% VALUBusy ->
// binder is VALU issue + waits, half of it bf16 unpack shifts/ands.
//  - gathers consumed via fmaf(w,(float)h,acc) -> v_fma_mix_f32 (no unpack)
//  - raw base + (b<<7)+lane*8 32-bit voffset -> saddr loads (no 64-bit adds)
//  - indirect loop unroll 4 (8 gathers in flight; FETCH is at compulsory floor,
//    drift no longer a hazard)

constexpr int BATCH = 1024;
constexpr int DIN = 128;
constexpr int DENSITY = 259;
constexpr int ODIM = 64;
constexpr int IDIM = 512;
constexpr int SLICES = 8;           // = #XCDs; 8 outputs / 64 indirect cols each
constexpr int RPB = 8;              // batch rows per block
constexpr int TPB = 512;            // 8 waves; wave wv: rows 2*(wv&3),+1; dims (wv>>2)*64..+63
constexpr int ROWS = DIN * DENSITY; // 33152 table rows
constexpr size_t WSI_ELEMS = (size_t)SLICES * ROWS * 64;  // fp16 indirect repack
constexpr size_t WSD_ELEMS = (size_t)SLICES * ROWS * 8;   // fp16 direct repack
constexpr size_t WS_NEEDED = (WSI_ELEMS + WSD_ELEMS) * 2; // 38,191,104 B

typedef _Float16 h4 __attribute__((ext_vector_type(4)));
typedef _Float16 h2 __attribute__((ext_vector_type(2)));

__device__ __forceinline__ void fma4(float4& a, float s, const float4 v) {
    a.x = fmaf(s, v.x, a.x);
    a.y = fmaf(s, v.y, a.y);
    a.z = fmaf(s, v.z, a.z);
    a.w = fmaf(s, v.w, a.w);
}

__device__ __forceinline__ void fma4h(float4& a, float s, const h4 v) {
    a.x = fmaf(s, (float)v[0], a.x);   // -> v_fma_mix_f32
    a.y = fmaf(s, (float)v[1], a.y);
    a.z = fmaf(s, (float)v[2], a.z);
    a.w = fmaf(s, (float)v[3], a.w);
}

__device__ __forceinline__ void add4(float4& a, const float4 t) {
    a.x += t.x; a.y += t.y; a.z += t.z; a.w += t.w;
}

__device__ __forceinline__ float4 shfl_xor4(float4 v, int m) {
    return make_float4(__shfl_xor(v.x, m), __shfl_xor(v.y, m),
                       __shfl_xor(v.z, m), __shfl_xor(v.w, m));
}

// ---- repack kernel: both tables -> slice-major fp16 in ws (float4 reads).
// blocks [0, ROWS/2): itab, 2 rows per block (128 thr/row x float4).
// blocks [ROWS/2, ROWS/2 + ROWS/16): dtab, 16 rows per block (16 thr/row x float4).
__global__ __launch_bounds__(256) void repack_kernel(
    const float* __restrict__ dtab,
    const float* __restrict__ itab,
    _Float16* __restrict__ wsI,
    _Float16* __restrict__ wsD)
{
    const int bid = blockIdx.x;
    const int t   = threadIdx.x;
    if (bid < ROWS / 2) {
        const int row  = bid * 2 + (t >> 7);
        const int t128 = t & 127;
        const float4 v = *(const float4*)(itab + (size_t)row * IDIM + t128 * 4);
        h4 o = { (_Float16)v.x, (_Float16)v.y, (_Float16)v.z, (_Float16)v.w };
        const int slice = t128 >> 4;       // col = 4*t128; slice = col/64
        const int c4    = t128 & 15;       // quad index within 64-col stripe
        *((h4*)wsI + ((size_t)slice * ROWS + row) * 16 + c4) = o;
    } else {
        const int rb  = bid - ROWS / 2;
        const int row = rb * 16 + (t >> 4);
        const int j   = t & 15;
        const float4 v = *(const float4*)(dtab + (size_t)row * ODIM + j * 4);
        h4 o = { (_Float16)v.x, (_Float16)v.y, (_Float16)v.z, (_Float16)v.w };
        const int slice = j >> 1;          // col = 4j; slice = col/8
        const int jj2   = j & 1;           // h4 half within 8-col stripe
        *((h4*)wsD + ((size_t)slice * ROWS + row) * 2 + jj2) = o;
    }
}

// ---- main kernel, fp16 slice-major tables, 8 waves (2 rows x 64-dim half each)
__global__ __launch_bounds__(TPB) void abel_f16_kernel(
    const float* __restrict__ x,
    const _Float16* __restrict__ wsI,
    const _Float16* __restrict__ wsD,
    float* __restrict__ out)
{
    __shared__ float4 s_w[RPB][DIN];        // spline weights per (row, dim)
    __shared__ int    s_base[RPB][DIN];     // d*259 + floor(256*x)
    __shared__ float  s_zp[2][RPB][64];     // per-half indirect partials
    __shared__ float2 s_dp[2][RPB][4];      // per-half direct partials (8 cols)

    const int bid   = blockIdx.x;
    const int slice = bid & (SLICES - 1);   // round-robin -> XCD-pinned stripe
    const int chunk = bid >> 3;             // 0..127
    const int tid   = threadIdx.x;
    const int wv    = tid >> 6;             // 0..7
    const int half  = wv >> 2;              // dim half: 0 or 1
    const int wp    = wv & 3;               // row-pair index
    const int lane  = tid & 63;
    const int rowbase = chunk * RPB;
    const int r0 = 2 * wp, r1 = 2 * wp + 1;
    const int dBeg = half * 64;

    // ---- phase 1: weights + base row index for all (r,d) pairs (2 iters)
    for (int i = tid; i < RPB * DIN; i += TPB) {
        const int r = i >> 7;       // 0..7
        const int d = i & 127;
        float xv = x[(rowbase + r) * DIN + d];
        float t  = xv * 256.0f;     // scale = DENSITY-3 = 256
        float fl = floorf(t);
        float f  = t - fl;
        float f2 = f * f;
        float f3 = f2 * f;
        float om = 1.0f - f;
        float w0 = om * om * om * (1.0f / 6.0f);
        float w1 = (3.0f * f3 - 6.0f * f2 + 4.0f) * (1.0f / 6.0f);
        float w2 = (-3.0f * f3 + 3.0f * f2 + 3.0f * f + 1.0f) * (1.0f / 6.0f);
        float w3 = f3 * (1.0f / 6.0f);
        s_w[r][d]    = make_float4(w0, w1, w2, w3);
        s_base[r][d] = d * DENSITY + (int)fl;
    }
    __syncthreads();

    // ---- phase 2a: indirect stripe. lane = knot q (lane>>4) x col-quad c4 (lane&15).
    // Window = 512B contiguous; byte voffset = (base<<7) + lane*8 (saddr loads).
    const int q  = lane >> 4;
    const int c4 = lane & 15;
    const char* __restrict__ itRaw =
        (const char*)wsI + (size_t)slice * ROWS * 128;
    const int lane8 = lane * 8;

    float4 a0 = make_float4(0.f, 0.f, 0.f, 0.f);
    float4 a1 = make_float4(0.f, 0.f, 0.f, 0.f);

    #pragma unroll 4
    for (int d = dBeg; d < dBeg + 64; ++d) {
        const int   b0 = s_base[r0][d];
        const int   b1 = s_base[r1][d];
        const float w0 = ((const float*)&s_w[r0][d])[q];
        const float w1 = ((const float*)&s_w[r1][d])[q];
        const h4 u0 = *(const h4*)(itRaw + ((b0 << 7) + lane8));
        const h4 u1 = *(const h4*)(itRaw + ((b1 << 7) + lane8));
        fma4h(a0, w0, u0);
        fma4h(a1, w1, u1);
    }
    // reduce over knot q (lane bits 4-5)
    add4(a0, shfl_xor4(a0, 16));
    add4(a0, shfl_xor4(a0, 32));
    add4(a1, shfl_xor4(a1, 16));
    add4(a1, shfl_xor4(a1, 32));
    if (q == 0) {
        reinterpret_cast<float4*>(s_zp[half][r0])[c4] = a0;
        reinterpret_cast<float4*>(s_zp[half][r1])[c4] = a1;
    }

    // ---- phase 2b: direct stripe (8 cols), wave owns rows r0,r1 for its dim half.
    // lane = dd(2b, bits 4-5: 4 dims/iter) | qd(2b, bits 2-3: knot) | jj(2b, bits 0-1).
    // Byte voffset = (base<<4) + qd*16 + jj*4.
    const int dd = lane >> 4;
    const int qd = (lane >> 2) & 3;
    const int jj = lane & 3;
    const char* __restrict__ dtRaw =
        (const char*)wsD + (size_t)slice * ROWS * 16;
    const int laneOffD = qd * 16 + jj * 4;

    float2 aD0 = make_float2(0.f, 0.f);
    float2 aD1 = make_float2(0.f, 0.f);
    #pragma unroll 2
    for (int d0 = dBeg; d0 < dBeg + 64; d0 += 4) {
        const int   dA  = d0 + dd;
        const int   bD0 = s_base[r0][dA];
        const int   bD1 = s_base[r1][dA];
        const float wD0 = ((const float*)&s_w[r0][dA])[qd];
        const float wD1 = ((const float*)&s_w[r1][dA])[qd];
        const h2 g0 = *(const h2*)(dtRaw + ((bD0 << 4) + laneOffD));
        const h2 g1 = *(const h2*)(dtRaw + ((bD1 << 4) + laneOffD));
        aD0.x = fmaf(wD0, (float)g0[0], aD0.x);
        aD0.y = fmaf(wD0, (float)g0[1], aD0.y);
        aD1.x = fmaf(wD1, (float)g1[0], aD1.x);
        aD1.y = fmaf(wD1, (float)g1[1], aD1.y);
    }
    // reduce over qd (bits 2-3) and dd (bits 4-5); jj (bits 0-1) = col pair
    aD0 = make_float2(aD0.x + __shfl_xor(aD0.x, 4), aD0.y + __shfl_xor(aD0.y, 4));
    aD0 = make_float2(aD0.x + __shfl_xor(aD0.x, 8), aD0.y + __shfl_xor(aD0.y, 8));
    aD0 = make_float2(aD0.x + __shfl_xor(aD0.x, 16), aD0.y + __shfl_xor(aD0.y, 16));
    aD0 = make_float2(aD0.x + __shfl_xor(aD0.x, 32), aD0.y + __shfl_xor(aD0.y, 32));
    aD1 = make_float2(aD1.x + __shfl_xor(aD1.x, 4), aD1.y + __shfl_xor(aD1.y, 4));
    aD1 = make_float2(aD1.x + __shfl_xor(aD1.x, 8), aD1.y + __shfl_xor(aD1.y, 8));
    aD1 = make_float2(aD1.x + __shfl_xor(aD1.x, 16), aD1.y + __shfl_xor(aD1.y, 16));
    aD1 = make_float2(aD1.x + __shfl_xor(aD1.x, 32), aD1.y + __shfl_xor(aD1.y, 32));
    if (lane < 4) {                      // lane == jj
        s_dp[half][r0][lane] = aD0;
        s_dp[half][r1][lane] = aD1;
    }
    __syncthreads();

    // ---- phase 3: epilogue, 64 threads = 8 rows x 8 outputs; sum the two halves
    if (tid < RPB * 8) {
        const int r  = tid >> 3;
        const int oo = tid & 7;
        float dir = ((const float*)&s_dp[0][r][0])[oo]
                  + ((const float*)&s_dp[1][r][0])[oo];
        const float* z0 = s_zp[0][r] + oo * 8;
        const float* z1 = s_zp[1][r] + oo * 8;
        float pos = __expf(z0[0] + z1[0]) + 0.25f * __expf(z0[1] + z1[1])
                  + (1.0f / 9.0f) * __expf(z0[2] + z1[2]) + 0.0625f * __expf(z0[3] + z1[3]);
        float neg = __expf(z0[4] + z1[4]) + 0.25f * __expf(z0[5] + z1[5])
                  + (1.0f / 9.0f) * __expf(z0[6] + z1[6]) + 0.0625f * __expf(z0[7] + z1[7]);
        out[(rowbase + r) * ODIM + slice * 8 + oo] = dir + pos - neg;
    }
}

// ---- fp32 fallback (round-7 kernel) for ws_size < WS_NEEDED
__global__ __launch_bounds__(256) void abel_fp32_kernel(
    const float* __restrict__ x,
    const float* __restrict__ dtab,
    const float* __restrict__ itab,
    float* __restrict__ out)
{
    __shared__ float4 s_w[RPB][DIN];
    __shared__ int    s_base[RPB][DIN];
    __shared__ float  s_z[RPB][64];
    __shared__ float4 s_dir4[RPB][2];

    const int bid   = blockIdx.x;
    const int slice = bid & (SLICES - 1);
    const int chunk = bid >> 3;
    const int tid   = threadIdx.x;
    const int wv    = tid >> 6;
    const int lane  = tid & 63;
    const int rowbase = chunk * RPB;

    for (int i = tid; i < RPB * DIN; i += 256) {
        const int r = i >> 7;
        const int d = i & 127;
        float xv = x[(rowbase + r) * DIN + d];
        float t  = xv * 256.0f;
        float fl = floorf(t);
        float f  = t - fl;
        float f2 = f * f;
        float f3 = f2 * f;
        float om = 1.0f - f;
        float w0 = om * om * om * (1.0f / 6.0f);
        float w1 = (3.0f * f3 - 6.0f * f2 + 4.0f) * (1.0f / 6.0f);
        float w2 = (-3.0f * f3 + 3.0f * f2 + 3.0f * f + 1.0f) * (1.0f / 6.0f);
        float w3 = f3 * (1.0f / 6.0f);
        s_w[r][d]    = make_float4(w0, w1, w2, w3);
        s_base[r][d] = d * DENSITY + (int)fl;
    }
    __syncthreads();

    const int q  = lane >> 4;
    const int c4 = lane & 15;
    const float* __restrict__ itL = itab + (size_t)q * IDIM + slice * 64 + c4 * 4;
    const int r0 = 2 * wv, r1 = 2 * wv + 1;

    float4 a0 = make_float4(0.f, 0.f, 0.f, 0.f);
    float4 a1 = make_float4(0.f, 0.f, 0.f, 0.f);
    #pragma unroll 2
    for (int d = 0; d < DIN; ++d) {
        const int   b0 = s_base[r0][d];
        const int   b1 = s_base[r1][d];
        const float w0 = ((const float*)&s_w[r0][d])[q];
        const float w1 = ((const float*)&s_w[r1][d])[q];
        float4 v0 = *(const float4*)(itL + (size_t)b0 * IDIM);
        float4 v1 = *(const float4*)(itL + (size_t)b1 * IDIM);
        fma4(a0, w0, v0);
        fma4(a1, w1, v1);
    }
    add4(a0, shfl_xor4(a0, 16));
    add4(a0, shfl_xor4(a0, 32));
    add4(a1, shfl_xor4(a1, 16));
    add4(a1, shfl_xor4(a1, 32));
    if (q == 0) {
        reinterpret_cast<float4*>(s_z[r0])[c4] = a0;
        reinterpret_cast<float4*>(s_z[r1])[c4] = a1;
    }

    const int dd = lane >> 3;
    const int qD = (lane >> 1) & 3;
    const int jD = lane & 1;
    const float* __restrict__ dtL = dtab + (size_t)qD * ODIM + slice * 8 + jD * 4;

    float4 aD0 = make_float4(0.f, 0.f, 0.f, 0.f);
    float4 aD1 = make_float4(0.f, 0.f, 0.f, 0.f);
    #pragma unroll 2
    for (int d0 = 0; d0 < DIN; d0 += 8) {
        const int   dA  = d0 + dd;
        const int   bD0 = s_base[r0][dA];
        const int   bD1 = s_base[r1][dA];
        const float wD0 = ((const float*)&s_w[r0][dA])[qD];
        const float wD1 = ((const float*)&s_w[r1][dA])[qD];
        float4 u0 = *(const float4*)(dtL + (size_t)bD0 * ODIM);
        float4 u1 = *(const float4*)(dtL + (size_t)bD1 * ODIM);
        fma4(aD0, wD0, u0);
        fma4(aD1, wD1, u1);
    }
    add4(aD0, shfl_xor4(aD0, 2));
    add4(aD0, shfl_xor4(aD0, 4));
    add4(aD0, shfl_xor4(aD0, 8));
    add4(aD0, shfl_xor4(aD0, 16));
    add4(aD0, shfl_xor4(aD0, 32));
    add4(aD1, shfl_xor4(aD1, 2));
    add4(aD1, shfl_xor4(aD1, 4));
    add4(aD1, shfl_xor4(aD1, 8));
    add4(aD1, shfl_xor4(aD1, 16));
    add4(aD1, shfl_xor4(aD1, 32));
    if (lane < 2) {
        s_dir4[r0][lane] = aD0;
        s_dir4[r1][lane] = aD1;
    }
    __syncthreads();

    if (tid < RPB * 8) {
        const int r  = tid >> 3;
        const int oo = tid & 7;
        float dir = ((const float*)&s_dir4[r][oo >> 2])[oo & 3];
        const float* zp = s_z[r] + oo * 8;
        float pos = __expf(zp[0]) + 0.25f * __expf(zp[1])
                  + (1.0f / 9.0f) * __expf(zp[2]) + 0.0625f * __expf(zp[3]);
        float neg = __expf(zp[4]) + 0.25f * __expf(zp[5])
                  + (1.0f / 9.0f) * __expf(zp[6]) + 0.0625f * __expf(zp[7]);
        out[(rowbase + r) * ODIM + slice * 8 + oo] = dir + pos - neg;
    }
}

extern "C" void kernel_launch(void* const* d_in, const int* in_sizes, int n_in,
                              void* d_out, int out_size, void* d_ws, size_t ws_size,
                              hipStream_t stream) {
    const float* x    = (const float*)d_in[0];
    const float* dtab = (const float*)d_in[1];
    const float* itab = (const float*)d_in[2];
    float* out = (float*)d_out;

    if (ws_size >= WS_NEEDED) {
        _Float16* wsI = (_Float16*)d_ws;
        _Float16* wsD = wsI + WSI_ELEMS;
        hipLaunchKernelGGL(repack_kernel, dim3(ROWS / 2 + ROWS / 16), dim3(256), 0, stream,
                           dtab, itab, wsI, wsD);
        hipLaunchKernelGGL(abel_f16_kernel, dim3(BATCH / RPB * SLICES), dim3(TPB), 0, stream,
                           x, wsI, wsD, out);
    } else {
        hipLaunchKernelGGL(abel_fp32_kernel, dim3(BATCH / RPB * SLICES), dim3(256), 0, stream,
                           x, dtab, itab, out);
    }
}

// Round 12
// 55.109 us; speedup vs baseline: 1.5404x; 1.0791x over previous
//
#include <hip/hip_runtime.h>

// ABELSpline: B=1024, D=128, DENSITY=259, ODIM=64, IDIM=512
// out[b,o] = direct[b,o] + sum_n c_n*(exp(z[b,8o+n]) - exp(z[b,8o+4+n])), c_n=(n+1)^-2
// direct[b,o] = sum_{d,k} w[b,d,k] * dtab[d*259 + p[b,d] + k, o]
// z[b,j]      = sum_{d,k} w[b,d,k] * itab[d*259 + p[b,d] + k, j]
// p = floor(256*x); p+3 <= 258 so the reference's mod never wraps.
//
// Round 11: WIDE GATHERS. R9 (2x occupancy) and R10 (fewer VALU ops) were both
// flat at ~43-45us -> binder is memory-request slots (measured effective MLP
// ~15 loads/CU vs ~5100 requests/CU). Halve request count at identical bytes:
// 16B/lane dwordx4 gathers. Indirect: one 1024B wave-load covers TWO dim
// windows (lane = h|q|c8), 64 loads/wave (was 128). Direct: one load covers
// SIXTEEN dims (lane = dd16|q), 8 loads/wave (was 32). Identical cache lines
// touched -> clean test of request-bound vs line-bound.

constexpr int BATCH = 1024;
constexpr int DIN = 128;
constexpr int DENSITY = 259;
constexpr int ODIM = 64;
constexpr int IDIM = 512;
constexpr int SLICES = 8;           // = #XCDs; 8 outputs / 64 indirect cols each
constexpr int RPB = 8;              // batch rows per block
constexpr int TPB = 512;            // 8 waves; wave wv: rows 2*(wv&3),+1; dims (wv>>2)*64..+63
constexpr int ROWS = DIN * DENSITY; // 33152 table rows
constexpr size_t WSI_ELEMS = (size_t)SLICES * ROWS * 64;  // fp16 indirect repack
constexpr size_t WSD_ELEMS = (size_t)SLICES * ROWS * 8;   // fp16 direct repack
constexpr size_t WS_NEEDED = (WSI_ELEMS + WSD_ELEMS) * 2; // 38,191,104 B

typedef _Float16 h8 __attribute__((ext_vector_type(8)));
typedef _Float16 h4 __attribute__((ext_vector_type(4)));

__device__ __forceinline__ void fma4(float4& a, float s, const float4 v) {
    a.x = fmaf(s, v.x, a.x);
    a.y = fmaf(s, v.y, a.y);
    a.z = fmaf(s, v.z, a.z);
    a.w = fmaf(s, v.w, a.w);
}

__device__ __forceinline__ void fma8h(float4& lo, float4& hi, float s, const h8 v) {
    lo.x = fmaf(s, (float)v[0], lo.x);   // -> v_fma_mix_f32
    lo.y = fmaf(s, (float)v[1], lo.y);
    lo.z = fmaf(s, (float)v[2], lo.z);
    lo.w = fmaf(s, (float)v[3], lo.w);
    hi.x = fmaf(s, (float)v[4], hi.x);
    hi.y = fmaf(s, (float)v[5], hi.y);
    hi.z = fmaf(s, (float)v[6], hi.z);
    hi.w = fmaf(s, (float)v[7], hi.w);
}

__device__ __forceinline__ void add4(float4& a, const float4 t) {
    a.x += t.x; a.y += t.y; a.z += t.z; a.w += t.w;
}

__device__ __forceinline__ float4 shfl_xor4(float4 v, int m) {
    return make_float4(__shfl_xor(v.x, m), __shfl_xor(v.y, m),
                       __shfl_xor(v.z, m), __shfl_xor(v.w, m));
}

// ---- repack kernel: both tables -> slice-major fp16 in ws (float4 reads).
__global__ __launch_bounds__(256) void repack_kernel(
    const float* __restrict__ dtab,
    const float* __restrict__ itab,
    _Float16* __restrict__ wsI,
    _Float16* __restrict__ wsD)
{
    const int bid = blockIdx.x;
    const int t   = threadIdx.x;
    if (bid < ROWS / 2) {
        const int row  = bid * 2 + (t >> 7);
        const int t128 = t & 127;
        const float4 v = *(const float4*)(itab + (size_t)row * IDIM + t128 * 4);
        h4 o = { (_Float16)v.x, (_Float16)v.y, (_Float16)v.z, (_Float16)v.w };
        const int slice = t128 >> 4;       // col = 4*t128; slice = col/64
        const int c4    = t128 & 15;       // quad index within 64-col stripe
        *((h4*)wsI + ((size_t)slice * ROWS + row) * 16 + c4) = o;
    } else {
        const int rb  = bid - ROWS / 2;
        const int row = rb * 16 + (t >> 4);
        const int j   = t & 15;
        const float4 v = *(const float4*)(dtab + (size_t)row * ODIM + j * 4);
        h4 o = { (_Float16)v.x, (_Float16)v.y, (_Float16)v.z, (_Float16)v.w };
        const int slice = j >> 1;          // col = 4j; slice = col/8
        const int jj2   = j & 1;           // h4 half within 8-col stripe
        *((h4*)wsD + ((size_t)slice * ROWS + row) * 2 + jj2) = o;
    }
}

// ---- main kernel, fp16 slice-major tables, wide 16B/lane gathers
__global__ __launch_bounds__(TPB) void abel_f16_kernel(
    const float* __restrict__ x,
    const _Float16* __restrict__ wsI,
    const _Float16* __restrict__ wsD,
    float* __restrict__ out)
{
    __shared__ float4 s_w[RPB][DIN];        // spline weights per (row, dim)
    __shared__ int    s_base[RPB][DIN];     // d*259 + floor(256*x)
    __shared__ float  s_zp[2][RPB][64];     // per-half indirect partials
    __shared__ float  s_dp[2][RPB][8];      // per-half direct partials (8 cols)

    const int bid   = blockIdx.x;
    const int slice = bid & (SLICES - 1);   // round-robin -> XCD-pinned stripe
    const int chunk = bid >> 3;             // 0..127
    const int tid   = threadIdx.x;
    const int wv    = tid >> 6;             // 0..7
    const int half  = wv >> 2;              // dim half: 0 or 1
    const int wp    = wv & 3;               // row-pair index
    const int lane  = tid & 63;
    const int rowbase = chunk * RPB;
    const int r0 = 2 * wp, r1 = 2 * wp + 1;
    const int dBeg = half * 64;

    // ---- phase 1: weights + base row index for all (r,d) pairs (2 iters)
    for (int i = tid; i < RPB * DIN; i += TPB) {
        const int r = i >> 7;       // 0..7
        const int d = i & 127;
        float xv = x[(rowbase + r) * DIN + d];
        float t  = xv * 256.0f;     // scale = DENSITY-3 = 256
        float fl = floorf(t);
        float f  = t - fl;
        float f2 = f * f;
        float f3 = f2 * f;
        float om = 1.0f - f;
        float w0 = om * om * om * (1.0f / 6.0f);
        float w1 = (3.0f * f3 - 6.0f * f2 + 4.0f) * (1.0f / 6.0f);
        float w2 = (-3.0f * f3 + 3.0f * f2 + 3.0f * f + 1.0f) * (1.0f / 6.0f);
        float w3 = f3 * (1.0f / 6.0f);
        s_w[r][d]    = make_float4(w0, w1, w2, w3);
        s_base[r][d] = d * DENSITY + (int)fl;
    }
    __syncthreads();

    // ---- phase 2a: indirect stripe, 16B/lane gathers, 2 dims per wave-load.
    // lane = hI (bit5: dim parity) | qI (bits 3-4: knot) | c8 (bits 0-2: col-oct)
    // byte voffset = (base<<7) + (qI<<7) + (c8<<4); one load covers dims d,d+1.
    const int c8 = lane & 7;
    const int qI = (lane >> 3) & 3;
    const int hI = lane >> 5;
    const char* __restrict__ itRaw = (const char*)wsI + (size_t)slice * ROWS * 128;
    const int laneOffI = (qI << 7) + (c8 << 4);

    float4 a0lo = make_float4(0.f, 0.f, 0.f, 0.f);
    float4 a0hi = make_float4(0.f, 0.f, 0.f, 0.f);
    float4 a1lo = make_float4(0.f, 0.f, 0.f, 0.f);
    float4 a1hi = make_float4(0.f, 0.f, 0.f, 0.f);

    #pragma unroll 4
    for (int d = dBeg; d < dBeg + 64; d += 2) {
        const int   dA = d + hI;
        const int   b0 = s_base[r0][dA];
        const int   b1 = s_base[r1][dA];
        const float w0 = ((const float*)&s_w[r0][dA])[qI];
        const float w1 = ((const float*)&s_w[r1][dA])[qI];
        const h8 u0 = *(const h8*)(itRaw + ((b0 << 7) + laneOffI));
        const h8 u1 = *(const h8*)(itRaw + ((b1 << 7) + laneOffI));
        fma8h(a0lo, a0hi, w0, u0);
        fma8h(a1lo, a1hi, w1, u1);
    }
    // reduce over qI (bits 3-4) and hI (bit 5)
    add4(a0lo, shfl_xor4(a0lo, 8));  add4(a0hi, shfl_xor4(a0hi, 8));
    add4(a0lo, shfl_xor4(a0lo, 16)); add4(a0hi, shfl_xor4(a0hi, 16));
    add4(a0lo, shfl_xor4(a0lo, 32)); add4(a0hi, shfl_xor4(a0hi, 32));
    add4(a1lo, shfl_xor4(a1lo, 8));  add4(a1hi, shfl_xor4(a1hi, 8));
    add4(a1lo, shfl_xor4(a1lo, 16)); add4(a1hi, shfl_xor4(a1hi, 16));
    add4(a1lo, shfl_xor4(a1lo, 32)); add4(a1hi, shfl_xor4(a1hi, 32));
    if (lane < 8) {   // lane == c8: owns cols c8*8..c8*8+7
        reinterpret_cast<float4*>(s_zp[half][r0])[c8 * 2]     = a0lo;
        reinterpret_cast<float4*>(s_zp[half][r0])[c8 * 2 + 1] = a0hi;
        reinterpret_cast<float4*>(s_zp[half][r1])[c8 * 2]     = a1lo;
        reinterpret_cast<float4*>(s_zp[half][r1])[c8 * 2 + 1] = a1hi;
    }

    // ---- phase 2b: direct stripe (8 cols), 16B/lane = 8 cols of one knot-row;
    // lane = dd16 (bits 2-5: 16 dims per load) | qD (bits 0-1: knot).
    // byte voffset = (base<<4) + (qD<<4).
    const int qD   = lane & 3;
    const int dd16 = lane >> 2;
    const char* __restrict__ dtRaw = (const char*)wsD + (size_t)slice * ROWS * 16;
    const int laneOffD = qD << 4;

    float4 aD0lo = make_float4(0.f, 0.f, 0.f, 0.f);
    float4 aD0hi = make_float4(0.f, 0.f, 0.f, 0.f);
    float4 aD1lo = make_float4(0.f, 0.f, 0.f, 0.f);
    float4 aD1hi = make_float4(0.f, 0.f, 0.f, 0.f);

    #pragma unroll
    for (int d0 = dBeg; d0 < dBeg + 64; d0 += 16) {
        const int   dA  = d0 + dd16;
        const int   bD0 = s_base[r0][dA];
        const int   bD1 = s_base[r1][dA];
        const float wD0 = ((const float*)&s_w[r0][dA])[qD];
        const float wD1 = ((const float*)&s_w[r1][dA])[qD];
        const h8 g0 = *(const h8*)(dtRaw + ((bD0 << 4) + laneOffD));
        const h8 g1 = *(const h8*)(dtRaw + ((bD1 << 4) + laneOffD));
        fma8h(aD0lo, aD0hi, wD0, g0);
        fma8h(aD1lo, aD1hi, wD1, g1);
    }
    // full-wave reduce (all lanes hold partials of the same 8 direct cols)
    #pragma unroll
    for (int m = 1; m <= 32; m <<= 1) {
        add4(aD0lo, shfl_xor4(aD0lo, m)); add4(aD0hi, shfl_xor4(aD0hi, m));
        add4(aD1lo, shfl_xor4(aD1lo, m)); add4(aD1hi, shfl_xor4(aD1hi, m));
    }
    if (lane == 0) {
        reinterpret_cast<float4*>(s_dp[half][r0])[0] = aD0lo;
        reinterpret_cast<float4*>(s_dp[half][r0])[1] = aD0hi;
        reinterpret_cast<float4*>(s_dp[half][r1])[0] = aD1lo;
        reinterpret_cast<float4*>(s_dp[half][r1])[1] = aD1hi;
    }
    __syncthreads();

    // ---- phase 3: epilogue, 64 threads = 8 rows x 8 outputs; sum the two halves
    if (tid < RPB * 8) {
        const int r  = tid >> 3;
        const int oo = tid & 7;
        float dir = s_dp[0][r][oo] + s_dp[1][r][oo];
        const float* z0 = s_zp[0][r] + oo * 8;
        const float* z1 = s_zp[1][r] + oo * 8;
        float pos = __expf(z0[0] + z1[0]) + 0.25f * __expf(z0[1] + z1[1])
                  + (1.0f / 9.0f) * __expf(z0[2] + z1[2]) + 0.0625f * __expf(z0[3] + z1[3]);
        float neg = __expf(z0[4] + z1[4]) + 0.25f * __expf(z0[5] + z1[5])
                  + (1.0f / 9.0f) * __expf(z0[6] + z1[6]) + 0.0625f * __expf(z0[7] + z1[7]);
        out[(rowbase + r) * ODIM + slice * 8 + oo] = dir + pos - neg;
    }
}

// ---- fp32 fallback (round-7 kernel) for ws_size < WS_NEEDED
__global__ __launch_bounds__(256) void abel_fp32_kernel(
    const float* __restrict__ x,
    const float* __restrict__ dtab,
    const float* __restrict__ itab,
    float* __restrict__ out)
{
    __shared__ float4 s_w[RPB][DIN];
    __shared__ int    s_base[RPB][DIN];
    __shared__ float  s_z[RPB][64];
    __shared__ float4 s_dir4[RPB][2];

    const int bid   = blockIdx.x;
    const int slice = bid & (SLICES - 1);
    const int chunk = bid >> 3;
    const int tid   = threadIdx.x;
    const int wv    = tid >> 6;
    const int lane  = tid & 63;
    const int rowbase = chunk * RPB;

    for (int i = tid; i < RPB * DIN; i += 256) {
        const int r = i >> 7;
        const int d = i & 127;
        float xv = x[(rowbase + r) * DIN + d];
        float t  = xv * 256.0f;
        float fl = floorf(t);
        float f  = t - fl;
        float f2 = f * f;
        float f3 = f2 * f;
        float om = 1.0f - f;
        float w0 = om * om * om * (1.0f / 6.0f);
        float w1 = (3.0f * f3 - 6.0f * f2 + 4.0f) * (1.0f / 6.0f);
        float w2 = (-3.0f * f3 + 3.0f * f2 + 3.0f * f + 1.0f) * (1.0f / 6.0f);
        float w3 = f3 * (1.0f / 6.0f);
        s_w[r][d]    = make_float4(w0, w1, w2, w3);
        s_base[r][d] = d * DENSITY + (int)fl;
    }
    __syncthreads();

    const int q  = lane >> 4;
    const int c4 = lane & 15;
    const float* __restrict__ itL = itab + (size_t)q * IDIM + slice * 64 + c4 * 4;
    const int r0 = 2 * wv, r1 = 2 * wv + 1;

    float4 a0 = make_float4(0.f, 0.f, 0.f, 0.f);
    float4 a1 = make_float4(0.f, 0.f, 0.f, 0.f);
    #pragma unroll 2
    for (int d = 0; d < DIN; ++d) {
        const int   b0 = s_base[r0][d];
        const int   b1 = s_base[r1][d];
        const float w0 = ((const float*)&s_w[r0][d])[q];
        const float w1 = ((const float*)&s_w[r1][d])[q];
        float4 v0 = *(const float4*)(itL + (size_t)b0 * IDIM);
        float4 v1 = *(const float4*)(itL + (size_t)b1 * IDIM);
        fma4(a0, w0, v0);
        fma4(a1, w1, v1);
    }
    add4(a0, shfl_xor4(a0, 16));
    add4(a0, shfl_xor4(a0, 32));
    add4(a1, shfl_xor4(a1, 16));
    add4(a1, shfl_xor4(a1, 32));
    if (q == 0) {
        reinterpret_cast<float4*>(s_z[r0])[c4] = a0;
        reinterpret_cast<float4*>(s_z[r1])[c4] = a1;
    }

    const int dd = lane >> 3;
    const int qD = (lane >> 1) & 3;
    const int jD = lane & 1;
    const float* __restrict__ dtL = dtab + (size_t)qD * ODIM + slice * 8 + jD * 4;

    float4 aD0 = make_float4(0.f, 0.f, 0.f, 0.f);
    float4 aD1 = make_float4(0.f, 0.f, 0.f, 0.f);
    #pragma unroll 2
    for (int d0 = 0; d0 < DIN; d0 += 8) {
        const int   dA  = d0 + dd;
        const int   bD0 = s_base[r0][dA];
        const int   bD1 = s_base[r1][dA];
        const float wD0 = ((const float*)&s_w[r0][dA])[qD];
        const float wD1 = ((const float*)&s_w[r1][dA])[qD];
        float4 u0 = *(const float4*)(dtL + (size_t)bD0 * ODIM);
        float4 u1 = *(const float4*)(dtL + (size_t)bD1 * ODIM);
        fma4(aD0, wD0, u0);
        fma4(aD1, wD1, u1);
    }
    add4(aD0, shfl_xor4(aD0, 2));
    add4(aD0, shfl_xor4(aD0, 4));
    add4(aD0, shfl_xor4(aD0, 8));
    add4(aD0, shfl_xor4(aD0, 16));
    add4(aD0, shfl_xor4(aD0, 32));
    add4(aD1, shfl_xor4(aD1, 2));
    add4(aD1, shfl_xor4(aD1, 4));
    add4(aD1, shfl_xor4(aD1, 8));
    add4(aD1, shfl_xor4(aD1, 16));
    add4(aD1, shfl_xor4(aD1, 32));
    if (lane < 2) {
        s_dir4[r0][lane] = aD0;
        s_dir4[r1][lane] = aD1;
    }
    __syncthreads();

    if (tid < RPB * 8) {
        const int r  = tid >> 3;
        const int oo = tid & 7;
        float dir = ((const float*)&s_dir4[r][oo >> 2])[oo & 3];
        const float* zp = s_z[r] + oo * 8;
        float pos = __expf(zp[0]) + 0.25f * __expf(zp[1])
                  + (1.0f / 9.0f) * __expf(zp[2]) + 0.0625f * __expf(zp[3]);
        float neg = __expf(zp[4]) + 0.25f * __expf(zp[5])
                  + (1.0f / 9.0f) * __expf(zp[6]) + 0.0625f * __expf(zp[7]);
        out[(rowbase + r) * ODIM + slice * 8 + oo] = dir + pos - neg;
    }
}

extern "C" void kernel_launch(void* const* d_in, const int* in_sizes, int n_in,
                              void* d_out, int out_size, void* d_ws, size_t ws_size,
                              hipStream_t stream) {
    const float* x    = (const float*)d_in[0];
    const float* dtab = (const float*)d_in[1];
    const float* itab = (const float*)d_in[2];
    float* out = (float*)d_out;

    if (ws_size >= WS_NEEDED) {
        _Float16* wsI = (_Float16*)d_ws;
        _Float16* wsD = wsI + WSI_ELEMS;
        hipLaunchKernelGGL(repack_kernel, dim3(ROWS / 2 + ROWS / 16), dim3(256), 0, stream,
                           dtab, itab, wsI, wsD);
        hipLaunchKernelGGL(abel_f16_kernel, dim3(BATCH / RPB * SLICES), dim3(TPB), 0, stream,
                           x, wsI, wsD, out);
    } else {
        hipLaunchKernelGGL(abel_fp32_kernel, dim3(BATCH / RPB * SLICES), dim3(256), 0, stream,
                           x, dtab, itab, out);
    }
}